// Round 2
// baseline (10273.206 us; speedup 1.0000x reference)
//
#include <hip/hip_runtime.h>
#include <hip/hip_bf16.h>
#include <math.h>

#define B_SZ 16
#define T_LR 2560
#define BT (B_SZ * T_LR)     // 40960 tokens
#define DM 256               // d_model
#define DI 512               // d_inner
#define DS 16                // d_state
#define DTR 16               // dt_rank
#define DBC_W 48             // dt_rank + 2*d_state

__device__ __forceinline__ float silu_f(float x) {
    return x / (1.f + __expf(-x));
}

// ---------------------------------------------------------------------------
// enc conv1: x(16,64,2560) -> e1(16,128,2560), k=3 same pad, silu
// ---------------------------------------------------------------------------
__global__ __launch_bounds__(256) void k_enc1(const float* __restrict__ x,
                                              const float* __restrict__ w,
                                              const float* __restrict__ bias,
                                              float* __restrict__ out) {
    int idx = blockIdx.x * 256 + threadIdx.x;       // b*128*2560
    int t = idx % T_LR;
    int c = (idx / T_LR) & 127;
    int b = idx / (T_LR * 128);
    float acc = bias[c];
    const float* wp = w + c * 64 * 3;
    const float* xp = x + (size_t)b * 64 * T_LR + t;
    #pragma unroll 4
    for (int ci = 0; ci < 64; ci++) {
        float w0 = wp[ci * 3 + 0], w1 = wp[ci * 3 + 1], w2 = wp[ci * 3 + 2];
        const float* xr = xp + (size_t)ci * T_LR;
        if (t > 0) acc += xr[-1] * w0;
        acc += xr[0] * w1;
        if (t < T_LR - 1) acc += xr[1] * w2;
    }
    out[idx] = silu_f(acc);
}

// ---------------------------------------------------------------------------
// enc conv2: e1(16,128,2560) -> t_buf(16,2560,256) [transposed!], silu
// ---------------------------------------------------------------------------
__global__ __launch_bounds__(256) void k_enc2(const float* __restrict__ e1,
                                              const float* __restrict__ w,
                                              const float* __restrict__ bias,
                                              float* __restrict__ out) {
    int b = blockIdx.y;
    int t0 = blockIdx.x * 16;
    int co = threadIdx.x;
    __shared__ float s[128][18];
    for (int i = threadIdx.x; i < 128 * 18; i += 256) {
        int ci = i / 18, dtt = i % 18;
        int t = t0 - 1 + dtt;
        s[ci][dtt] = (t >= 0 && t < T_LR) ? e1[((size_t)b * 128 + ci) * T_LR + t] : 0.f;
    }
    __syncthreads();
    float acc[16];
    float bi = bias[co];
    #pragma unroll
    for (int tt = 0; tt < 16; tt++) acc[tt] = bi;
    const float* wp = w + (size_t)co * 128 * 3;
    for (int ci = 0; ci < 128; ci++) {
        float w0 = wp[ci * 3], w1 = wp[ci * 3 + 1], w2 = wp[ci * 3 + 2];
        #pragma unroll
        for (int tt = 0; tt < 16; tt++)
            acc[tt] += s[ci][tt] * w0 + s[ci][tt + 1] * w1 + s[ci][tt + 2] * w2;
    }
    #pragma unroll
    for (int tt = 0; tt < 16; tt++)
        out[((size_t)b * T_LR + t0 + tt) * DM + co] = silu_f(acc[tt]);
}

// ---------------------------------------------------------------------------
// rmsnorm over last dim (256). One wave per token.
// ---------------------------------------------------------------------------
__global__ __launch_bounds__(256) void k_rmsnorm(const float* __restrict__ in1,
                                                 const float* __restrict__ w,
                                                 float* __restrict__ out, int ntok) {
    int tok = (blockIdx.x * 256 + threadIdx.x) >> 6;
    int lane = threadIdx.x & 63;
    if (tok >= ntok) return;
    float4 v = ((const float4*)(in1 + (size_t)tok * DM))[lane];
    float ss = v.x * v.x + v.y * v.y + v.z * v.z + v.w * v.w;
    #pragma unroll
    for (int off = 32; off > 0; off >>= 1) ss += __shfl_xor(ss, off);
    float sc = rsqrtf(ss * (1.f / 256.f) + 1e-6f);
    float4 wv = ((const float4*)w)[lane];
    float4 o;
    o.x = v.x * sc * wv.x; o.y = v.y * sc * wv.y;
    o.z = v.z * sc * wv.z; o.w = v.w * sc * wv.w;
    ((float4*)(out + (size_t)tok * DM))[lane] = o;
}

// ---------------------------------------------------------------------------
// generic tiled fp32 GEMM: C[M,N] = act(A[M,K] @ Bw[N,K]^T + bias) + res (+ C if accum)
// arev: A row read time-reversed within each T_LR segment; crev: C/res row written reversed
// act: 0 none, 2 softplus.  64x64 tile, 256 threads, 4x4 per thread.
// ---------------------------------------------------------------------------
__global__ __launch_bounds__(256) void k_gemm(const float* __restrict__ A, int lda,
                                              const float* __restrict__ Bw,
                                              float* C, int ldc,
                                              const float* __restrict__ bias,
                                              const float* __restrict__ res,
                                              int N, int K, int act, int arev, int crev,
                                              int accum) {
    __shared__ float As[16][68];
    __shared__ float Bs[16][68];
    int bm = blockIdx.x, bn = blockIdx.y;
    int tid = threadIdx.x;
    int tx = tid & 15, ty = tid >> 4;
    int lm = tid & 63, kq = tid >> 6;
    float acc[4][4] = {};
    int arow = bm * 64 + lm;
    int asrc = arev ? ((arow / T_LR) * T_LR + (T_LR - 1 - (arow % T_LR))) : arow;
    int brow = bn * 64 + lm;
    const float4* ap = (const float4*)(A + (size_t)asrc * lda) + kq;
    bool bvalid = brow < N;
    const float4* bp = (const float4*)(Bw + (size_t)brow * K) + kq;
    for (int k0 = 0; k0 < K; k0 += 16) {
        float4 av = ap[0]; ap += 4;
        float4 bv = make_float4(0.f, 0.f, 0.f, 0.f);
        if (bvalid) { bv = bp[0]; bp += 4; }
        As[kq * 4 + 0][lm] = av.x; As[kq * 4 + 1][lm] = av.y;
        As[kq * 4 + 2][lm] = av.z; As[kq * 4 + 3][lm] = av.w;
        Bs[kq * 4 + 0][lm] = bv.x; Bs[kq * 4 + 1][lm] = bv.y;
        Bs[kq * 4 + 2][lm] = bv.z; Bs[kq * 4 + 3][lm] = bv.w;
        __syncthreads();
        #pragma unroll
        for (int kk = 0; kk < 16; kk++) {
            float4 a = *(const float4*)&As[kk][ty * 4];
            float4 b = *(const float4*)&Bs[kk][tx * 4];
            acc[0][0] += a.x * b.x; acc[0][1] += a.x * b.y; acc[0][2] += a.x * b.z; acc[0][3] += a.x * b.w;
            acc[1][0] += a.y * b.x; acc[1][1] += a.y * b.y; acc[1][2] += a.y * b.z; acc[1][3] += a.y * b.w;
            acc[2][0] += a.z * b.x; acc[2][1] += a.z * b.y; acc[2][2] += a.z * b.z; acc[2][3] += a.z * b.w;
            acc[3][0] += a.w * b.x; acc[3][1] += a.w * b.y; acc[3][2] += a.w * b.z; acc[3][3] += a.w * b.w;
        }
        __syncthreads();
    }
    #pragma unroll
    for (int i = 0; i < 4; i++) {
        int mr = bm * 64 + ty * 4 + i;
        int orow = crev ? ((mr / T_LR) * T_LR + (T_LR - 1 - (mr % T_LR))) : mr;
        #pragma unroll
        for (int j = 0; j < 4; j++) {
            int n = bn * 64 + tx * 4 + j;
            if (n < N) {
                float v = acc[i][j];
                if (bias) v += bias[n];
                if (act == 2) v = (v > 20.f) ? v : log1pf(__expf(v));
                if (res) v += res[(size_t)orow * ldc + n];
                if (accum) v += C[(size_t)orow * ldc + n];
                C[(size_t)orow * ldc + n] = v;
            }
        }
    }
}

// ---------------------------------------------------------------------------
// depthwise causal conv k=4 + bias + silu.  xc (Tc,512) -> out (Tc,512)
// ---------------------------------------------------------------------------
__global__ __launch_bounds__(256) void k_dwconv(const float* __restrict__ xc,
                                                const float* __restrict__ cw,
                                                const float* __restrict__ cb,
                                                float* __restrict__ out) {
    int idx = blockIdx.x * 256 + threadIdx.x;   // Tc*512
    int d = idx & (DI - 1);
    int row = idx >> 9;
    int t = row % T_LR;
    float acc = cb[d];
    #pragma unroll
    for (int k = 0; k < 4; k++) {
        int tt = t - 3 + k;
        if (tt >= 0) acc += xc[(size_t)(row - t + tt) * DI + d] * cw[d * 4 + k];
    }
    out[idx] = silu_f(acc);
}

// ---------------------------------------------------------------------------
// selective scan: one thread per (b,d), 16 states in registers, T sequential.
// y may alias xcs (in-place): per-thread column read-then-write at same t.
// ---------------------------------------------------------------------------
__global__ __launch_bounds__(64) void k_scan(const float* __restrict__ dt,
                                             const float* xcs,
                                             const float* __restrict__ dbc,
                                             const float* __restrict__ Alog,
                                             const float* __restrict__ Dp,
                                             float* y) {
    int gid = blockIdx.x * 64 + threadIdx.x;    // bl*512 + d
    int d = gid & (DI - 1);
    int bl = gid >> 9;
    float A[DS], h[DS];
    #pragma unroll
    for (int n = 0; n < DS; n++) { A[n] = -__expf(Alog[d * DS + n]); h[n] = 0.f; }
    float Dd = Dp[d];
    const float* dtp = dt + (size_t)bl * T_LR * DI + d;
    const float* xp  = xcs + (size_t)bl * T_LR * DI + d;
    const float* bcp = dbc + (size_t)bl * T_LR * DBC_W;
    float* yp = y + (size_t)bl * T_LR * DI + d;
    for (int t = 0; t < T_LR; t++) {
        float dtv = dtp[(size_t)t * DI];
        float xv  = xp[(size_t)t * DI];
        float dtx = dtv * xv;
        const float* bc = bcp + (size_t)t * DBC_W;
        float acc = 0.f;
        #pragma unroll
        for (int n = 0; n < DS; n++) {
            float dA = __expf(dtv * A[n]);
            h[n] = dA * h[n] + dtx * bc[16 + n];
            acc += h[n] * bc[32 + n];
        }
        yp[(size_t)t * DI] = acc + xv * Dd;
    }
}

// ---------------------------------------------------------------------------
// gating: y *= silu(z), elementwise (Tc*512)
// ---------------------------------------------------------------------------
__global__ __launch_bounds__(256) void k_gate(float* __restrict__ y,
                                              const float* __restrict__ z) {
    int idx = blockIdx.x * 256 + threadIdx.x;
    y[idx] = y[idx] * silu_f(z[idx]);
}

// ---------------------------------------------------------------------------
// convd (512ch -> 256ch, k=3 same) + batchnorm + silu.
// ---------------------------------------------------------------------------
__global__ __launch_bounds__(256) void k_convd(const float* __restrict__ comb,
                                               const float* __restrict__ tb,
                                               const float* __restrict__ w,
                                               const float* __restrict__ bias,
                                               const float* __restrict__ bng,
                                               const float* __restrict__ bnb,
                                               const float* __restrict__ bnm,
                                               const float* __restrict__ bnv,
                                               float* __restrict__ out) {
    int b = blockIdx.y;
    int t0 = blockIdx.x * 16;
    int co = threadIdx.x;
    __shared__ float s[64][18];
    float acc[16] = {};
    const float* wp = w + (size_t)co * 512 * 3;
    for (int cc = 0; cc < 8; cc++) {
        __syncthreads();
        for (int i = threadIdx.x; i < 64 * 18; i += 256) {
            int ci_l = i & 63, dtt = i >> 6;
            int ci = cc * 64 + ci_l;
            int t = t0 - 1 + dtt;
            float v = 0.f;
            if (t >= 0 && t < T_LR)
                v = (ci < 256) ? comb[((size_t)b * T_LR + t) * DM + ci]
                               : tb[((size_t)b * T_LR + t) * DM + ci - 256];
            s[ci_l][dtt] = v;
        }
        __syncthreads();
        for (int ci_l = 0; ci_l < 64; ci_l++) {
            int ci = cc * 64 + ci_l;
            float w0 = wp[ci * 3], w1 = wp[ci * 3 + 1], w2 = wp[ci * 3 + 2];
            #pragma unroll
            for (int tt = 0; tt < 16; tt++)
                acc[tt] += s[ci_l][tt] * w0 + s[ci_l][tt + 1] * w1 + s[ci_l][tt + 2] * w2;
        }
    }
    float scale = rsqrtf(bnv[co] + 1e-5f) * bng[co];
    float shift = bnb[co] - bnm[co] * scale;
    float bi = bias[co];
    #pragma unroll
    for (int tt = 0; tt < 16; tt++) {
        float v = (acc[tt] + bi) * scale + shift;
        out[((size_t)b * T_LR + t0 + tt) * DM + co] = silu_f(v);
    }
}

// ---------------------------------------------------------------------------
// sp conv (256ch -> 128ch, k=3 same) + pixel shuffle (R=2) -> d_out
// ---------------------------------------------------------------------------
__global__ __launch_bounds__(128) void k_sp(const float* __restrict__ din,
                                            const float* __restrict__ w,
                                            const float* __restrict__ bias,
                                            float* __restrict__ out) {
    int b = blockIdx.y;
    int t0 = blockIdx.x * 16;
    int c = threadIdx.x;    // 0..127
    __shared__ float s[64][18];
    float acc[16];
    float bi = bias[c];
    #pragma unroll
    for (int tt = 0; tt < 16; tt++) acc[tt] = bi;
    const float* wp = w + (size_t)c * 256 * 3;
    for (int cc = 0; cc < 4; cc++) {
        __syncthreads();
        for (int i = threadIdx.x; i < 64 * 18; i += 128) {
            int ci_l = i & 63, dtt = i >> 6;
            int ci = cc * 64 + ci_l;
            int t = t0 - 1 + dtt;
            float v = 0.f;
            if (t >= 0 && t < T_LR) v = din[((size_t)b * T_LR + t) * DM + ci];
            s[ci_l][dtt] = v;
        }
        __syncthreads();
        for (int ci_l = 0; ci_l < 64; ci_l++) {
            int ci = cc * 64 + ci_l;
            float w0 = wp[ci * 3], w1 = wp[ci * 3 + 1], w2 = wp[ci * 3 + 2];
            #pragma unroll
            for (int tt = 0; tt < 16; tt++)
                acc[tt] += s[ci_l][tt] * w0 + s[ci_l][tt + 1] * w1 + s[ci_l][tt + 2] * w2;
        }
    }
    int c2 = c >> 1, r = c & 1;
    #pragma unroll
    for (int tt = 0; tt < 16; tt++) {
        size_t oi = (((size_t)b * 64 + c2) * T_LR + t0 + tt) * 2 + r;
        out[oi] = acc[tt];
    }
}

// ---------------------------------------------------------------------------
extern "C" void kernel_launch(void* const* d_in, const int* in_sizes, int n_in,
                              void* d_out, int out_size, void* d_ws, size_t ws_size,
                              hipStream_t stream) {
    const float* x       = (const float*)d_in[0];
    const float* enc_w1  = (const float*)d_in[1];
    const float* enc_b1  = (const float*)d_in[2];
    const float* enc_w2  = (const float*)d_in[3];
    const float* enc_b2  = (const float*)d_in[4];
    const float* norm1_w = (const float*)d_in[5];
    const float* norm2_w = (const float*)d_in[6];
    const float* convd_w = (const float*)d_in[25];
    const float* convd_b = (const float*)d_in[26];
    const float* bn_g    = (const float*)d_in[27];
    const float* bn_b    = (const float*)d_in[28];
    const float* bn_mean = (const float*)d_in[29];
    const float* bn_var  = (const float*)d_in[30];
    const float* sp_w    = (const float*)d_in[31];
    const float* sp_b    = (const float*)d_in[32];
    float* out = (float*)d_out;

    // ---- workspace layout (floats) ----
    // persistent: t_buf, xn_buf, mo (each BT*DM) = 126 MB
    // scratch: P1 (Tc*DI) | P2 (Tc*DI) | dbc (Tc*DBC_W), Tc = Bc*T_LR
    float* ws = (float*)d_ws;
    size_t availf = ws_size / sizeof(float);
    float* t_buf  = ws;
    float* xn_buf = ws + (size_t)BT * DM;
    float* mo     = ws + 2 * (size_t)BT * DM;
    float* scratch = ws + 3 * (size_t)BT * DM;
    size_t persist = 3 * (size_t)BT * DM;
    size_t scratch_avail = (availf > persist) ? (availf - persist) : 0;
    int Bc = 16;
    while (Bc > 1 && (size_t)Bc * T_LR * (2 * DI + DBC_W) > scratch_avail) Bc >>= 1;

    float* e1 = mo;   // 16*128*2560 = 5.24M floats fits in mo (10.49M); dead before out_proj

    // encoder
    k_enc1<<<(B_SZ * 128 * T_LR) / 256, 256, 0, stream>>>(x, enc_w1, enc_b1, e1);
    k_enc2<<<dim3(T_LR / 16, B_SZ), 256, 0, stream>>>(e1, enc_w2, enc_b2, t_buf);
    k_rmsnorm<<<BT / 4, 256, 0, stream>>>(t_buf, norm1_w, xn_buf, BT);

    for (int dir = 0; dir < 2; dir++) {
        const float* inW   = (const float*)d_in[7 + 9 * dir];
        const float* convW = (const float*)d_in[8 + 9 * dir];
        const float* convb = (const float*)d_in[9 + 9 * dir];
        const float* xW    = (const float*)d_in[10 + 9 * dir];
        const float* dtW   = (const float*)d_in[11 + 9 * dir];
        const float* dtb   = (const float*)d_in[12 + 9 * dir];
        const float* Alog  = (const float*)d_in[13 + 9 * dir];
        const float* Dp    = (const float*)d_in[14 + 9 * dir];
        const float* outW  = (const float*)d_in[15 + 9 * dir];
        int rev = dir;
        for (int b0 = 0; b0 < B_SZ; b0 += Bc) {
            int Tc = Bc * T_LR;
            float* P1  = scratch;
            float* P2  = scratch + (size_t)Tc * DI;
            float* db  = scratch + 2 * (size_t)Tc * DI;
            const float* xnC = xn_buf + (size_t)b0 * T_LR * DM;
            float*       moC = mo     + (size_t)b0 * T_LR * DM;
            // xc_pre = xn(rev) @ inW[0:512]^T  -> P1
            k_gemm<<<dim3(Tc / 64, 8), 256, 0, stream>>>(xnC, DM, inW, P1, DI,
                                                         nullptr, nullptr, DI, DM, 0, rev, 0, 0);
            // depthwise causal conv + silu -> P2 (xcs)
            k_dwconv<<<((size_t)Tc * DI) / 256, 256, 0, stream>>>(P1, convW, convb, P2);
            // dbc = xcs @ xW^T -> db
            k_gemm<<<dim3(Tc / 64, 1), 256, 0, stream>>>(P2, DI, xW, db, DBC_W,
                                                         nullptr, nullptr, DBC_W, DI, 0, 0, 0, 0);
            // dt = softplus(dbc[:, :16] @ dtW^T + dtb) -> P1 (xc_pre dead)
            k_gemm<<<dim3(Tc / 64, 8), 256, 0, stream>>>(db, DBC_W, dtW, P1, DI,
                                                         dtb, nullptr, DI, DTR, 2, 0, 0, 0);
            // selective scan: y written in place over P2
            k_scan<<<(Bc * DI) / 64, 64, 0, stream>>>(P1, P2, db, Alog, Dp, P2);
            // z = xn(rev) @ inW[512:1024]^T -> P1 (dt dead)
            k_gemm<<<dim3(Tc / 64, 8), 256, 0, stream>>>(xnC, DM, inW + (size_t)DI * DM, P1, DI,
                                                         nullptr, nullptr, DI, DM, 0, rev, 0, 0);
            // y *= silu(z)
            k_gate<<<((size_t)Tc * DI) / 256, 256, 0, stream>>>(P2, P1);
            // mo (+)= y @ outW^T + xn   (crev for backward direction)
            k_gemm<<<dim3(Tc / 64, 4), 256, 0, stream>>>(P2, DI, outW, moC, DM,
                                                         nullptr, xnC, DM, DI, 0, 0, rev, dir);
        }
    }

    // combined = rmsnorm(mo) -> comb (reuses xn_buf, now dead)
    float* comb = xn_buf;
    k_rmsnorm<<<BT / 4, 256, 0, stream>>>(mo, norm2_w, comb, BT);
    // convd + bn + silu -> d_buf (reuses mo, now dead)
    float* d_buf = mo;
    k_convd<<<dim3(T_LR / 16, B_SZ), 256, 0, stream>>>(comb, t_buf, convd_w, convd_b,
                                                       bn_g, bn_b, bn_mean, bn_var, d_buf);
    // sp conv + pixel shuffle -> out
    k_sp<<<dim3(T_LR / 16, B_SZ), 128, 0, stream>>>(d_buf, sp_w, sp_b, out);
}

// Round 3
// 3921.787 us; speedup vs baseline: 2.6195x; 2.6195x over previous
//
#include <hip/hip_runtime.h>
#include <hip/hip_bf16.h>
#include <math.h>

#define B_SZ 16
#define T_LR 2560
#define BT (B_SZ * T_LR)     // 40960 tokens
#define DM 256               // d_model
#define DI 512               // d_inner
#define DS 16                // d_state
#define DTR 16               // dt_rank
#define DBC_W 48             // dt_rank + 2*d_state
#define CH 64                // scan chunks per sequence
#define CLEN (T_LR / CH)     // 40 steps per chunk

__device__ __forceinline__ float silu_f(float x) {
    return x / (1.f + __expf(-x));
}

// ---------------------------------------------------------------------------
// enc conv1: x(16,64,2560) -> e1(16,128,2560), k=3 same pad, silu
// ---------------------------------------------------------------------------
__global__ __launch_bounds__(256) void k_enc1(const float* __restrict__ x,
                                              const float* __restrict__ w,
                                              const float* __restrict__ bias,
                                              float* __restrict__ out) {
    int idx = blockIdx.x * 256 + threadIdx.x;       // b*128*2560
    int t = idx % T_LR;
    int c = (idx / T_LR) & 127;
    int b = idx / (T_LR * 128);
    float acc = bias[c];
    const float* wp = w + c * 64 * 3;
    const float* xp = x + (size_t)b * 64 * T_LR + t;
    #pragma unroll 4
    for (int ci = 0; ci < 64; ci++) {
        float w0 = wp[ci * 3 + 0], w1 = wp[ci * 3 + 1], w2 = wp[ci * 3 + 2];
        const float* xr = xp + (size_t)ci * T_LR;
        if (t > 0) acc += xr[-1] * w0;
        acc += xr[0] * w1;
        if (t < T_LR - 1) acc += xr[1] * w2;
    }
    out[idx] = silu_f(acc);
}

// ---------------------------------------------------------------------------
// enc conv2: e1(16,128,2560) -> t_buf(16,2560,256) [transposed!], silu
// ---------------------------------------------------------------------------
__global__ __launch_bounds__(256) void k_enc2(const float* __restrict__ e1,
                                              const float* __restrict__ w,
                                              const float* __restrict__ bias,
                                              float* __restrict__ out) {
    int b = blockIdx.y;
    int t0 = blockIdx.x * 16;
    int co = threadIdx.x;
    __shared__ float s[128][18];
    for (int i = threadIdx.x; i < 128 * 18; i += 256) {
        int ci = i / 18, dtt = i % 18;
        int t = t0 - 1 + dtt;
        s[ci][dtt] = (t >= 0 && t < T_LR) ? e1[((size_t)b * 128 + ci) * T_LR + t] : 0.f;
    }
    __syncthreads();
    float acc[16];
    float bi = bias[co];
    #pragma unroll
    for (int tt = 0; tt < 16; tt++) acc[tt] = bi;
    const float* wp = w + (size_t)co * 128 * 3;
    for (int ci = 0; ci < 128; ci++) {
        float w0 = wp[ci * 3], w1 = wp[ci * 3 + 1], w2 = wp[ci * 3 + 2];
        #pragma unroll
        for (int tt = 0; tt < 16; tt++)
            acc[tt] += s[ci][tt] * w0 + s[ci][tt + 1] * w1 + s[ci][tt + 2] * w2;
    }
    #pragma unroll
    for (int tt = 0; tt < 16; tt++)
        out[((size_t)b * T_LR + t0 + tt) * DM + co] = silu_f(acc[tt]);
}

// ---------------------------------------------------------------------------
// rmsnorm over last dim (256). One wave per token.
// ---------------------------------------------------------------------------
__global__ __launch_bounds__(256) void k_rmsnorm(const float* __restrict__ in1,
                                                 const float* __restrict__ w,
                                                 float* __restrict__ out, int ntok) {
    int tok = (blockIdx.x * 256 + threadIdx.x) >> 6;
    int lane = threadIdx.x & 63;
    if (tok >= ntok) return;
    float4 v = ((const float4*)(in1 + (size_t)tok * DM))[lane];
    float ss = v.x * v.x + v.y * v.y + v.z * v.z + v.w * v.w;
    #pragma unroll
    for (int off = 32; off > 0; off >>= 1) ss += __shfl_xor(ss, off);
    float sc = rsqrtf(ss * (1.f / 256.f) + 1e-6f);
    float4 wv = ((const float4*)w)[lane];
    float4 o;
    o.x = v.x * sc * wv.x; o.y = v.y * sc * wv.y;
    o.z = v.z * sc * wv.z; o.w = v.w * sc * wv.w;
    ((float4*)(out + (size_t)tok * DM))[lane] = o;
}

// ---------------------------------------------------------------------------
// generic tiled fp32 GEMM: C[M,N] = act(A[M,K] @ Bw[N,K]^T + bias) + res (+ C if accum)
// Agate: if non-null, A is elementwise multiplied by silu(Agate) during staging.
// arev: A row read time-reversed within each T_LR segment; crev: C/res row written reversed
// act: 0 none, 2 softplus.  64x64 tile, 256 threads, 4x4 per thread.
// ---------------------------------------------------------------------------
__global__ __launch_bounds__(256) void k_gemm(const float* __restrict__ A, int lda,
                                              const float* __restrict__ Agate,
                                              const float* __restrict__ Bw,
                                              float* C, int ldc,
                                              const float* __restrict__ bias,
                                              const float* __restrict__ res,
                                              int N, int K, int act, int arev, int crev,
                                              int accum) {
    __shared__ float As[16][68];
    __shared__ float Bs[16][68];
    int bm = blockIdx.x, bn = blockIdx.y;
    int tid = threadIdx.x;
    int tx = tid & 15, ty = tid >> 4;
    int lm = tid & 63, kq = tid >> 6;
    float acc[4][4] = {};
    int arow = bm * 64 + lm;
    int asrc = arev ? ((arow / T_LR) * T_LR + (T_LR - 1 - (arow % T_LR))) : arow;
    int brow = bn * 64 + lm;
    const float4* ap = (const float4*)(A + (size_t)asrc * lda) + kq;
    const float4* gp = Agate ? (const float4*)(Agate + (size_t)asrc * lda) + kq : nullptr;
    bool bvalid = brow < N;
    const float4* bp = (const float4*)(Bw + (size_t)brow * K) + kq;
    for (int k0 = 0; k0 < K; k0 += 16) {
        float4 av = ap[0]; ap += 4;
        if (gp) {
            float4 gv = gp[0]; gp += 4;
            av.x *= silu_f(gv.x); av.y *= silu_f(gv.y);
            av.z *= silu_f(gv.z); av.w *= silu_f(gv.w);
        }
        float4 bv = make_float4(0.f, 0.f, 0.f, 0.f);
        if (bvalid) { bv = bp[0]; bp += 4; }
        As[kq * 4 + 0][lm] = av.x; As[kq * 4 + 1][lm] = av.y;
        As[kq * 4 + 2][lm] = av.z; As[kq * 4 + 3][lm] = av.w;
        Bs[kq * 4 + 0][lm] = bv.x; Bs[kq * 4 + 1][lm] = bv.y;
        Bs[kq * 4 + 2][lm] = bv.z; Bs[kq * 4 + 3][lm] = bv.w;
        __syncthreads();
        #pragma unroll
        for (int kk = 0; kk < 16; kk++) {
            float4 a = *(const float4*)&As[kk][ty * 4];
            float4 b = *(const float4*)&Bs[kk][tx * 4];
            acc[0][0] += a.x * b.x; acc[0][1] += a.x * b.y; acc[0][2] += a.x * b.z; acc[0][3] += a.x * b.w;
            acc[1][0] += a.y * b.x; acc[1][1] += a.y * b.y; acc[1][2] += a.y * b.z; acc[1][3] += a.y * b.w;
            acc[2][0] += a.z * b.x; acc[2][1] += a.z * b.y; acc[2][2] += a.z * b.z; acc[2][3] += a.z * b.w;
            acc[3][0] += a.w * b.x; acc[3][1] += a.w * b.y; acc[3][2] += a.w * b.z; acc[3][3] += a.w * b.w;
        }
        __syncthreads();
    }
    #pragma unroll
    for (int i = 0; i < 4; i++) {
        int mr = bm * 64 + ty * 4 + i;
        int orow = crev ? ((mr / T_LR) * T_LR + (T_LR - 1 - (mr % T_LR))) : mr;
        #pragma unroll
        for (int j = 0; j < 4; j++) {
            int n = bn * 64 + tx * 4 + j;
            if (n < N) {
                float v = acc[i][j];
                if (bias) v += bias[n];
                if (act == 2) v = (v > 20.f) ? v : log1pf(__expf(v));
                if (res) v += res[(size_t)orow * ldc + n];
                if (accum) v += C[(size_t)orow * ldc + n];
                C[(size_t)orow * ldc + n] = v;
            }
        }
    }
}

// ---------------------------------------------------------------------------
// depthwise causal conv k=4 + bias + silu.  xc (Tc,512) -> out (Tc,512)
// ---------------------------------------------------------------------------
__global__ __launch_bounds__(256) void k_dwconv(const float* __restrict__ xc,
                                                const float* __restrict__ cw,
                                                const float* __restrict__ cb,
                                                float* __restrict__ out) {
    int idx = blockIdx.x * 256 + threadIdx.x;   // Tc*512
    int d = idx & (DI - 1);
    int row = idx >> 9;
    int t = row % T_LR;
    float acc = cb[d];
    #pragma unroll
    for (int k = 0; k < 4; k++) {
        int tt = t - 3 + k;
        if (tt >= 0) acc += xc[(size_t)(row - t + tt) * DI + d] * cw[d * 4 + k];
    }
    out[idx] = silu_f(acc);
}

// ---------------------------------------------------------------------------
// scan phase 1: per (bl, chunk, d) thread. Chunk-local scan from h=0.
// Stores end state (DS floats) and sum of dt over chunk.
// ---------------------------------------------------------------------------
__global__ __launch_bounds__(256) void k_scan_p1(const float* __restrict__ dt,
                                                 const float* __restrict__ x,
                                                 const float* __restrict__ dbc,
                                                 const float* __restrict__ Alog,
                                                 float* __restrict__ hS,
                                                 float* __restrict__ csum) {
    int gid = blockIdx.x * 256 + threadIdx.x;   // (bl*CH + c)*DI + d
    int d = gid & (DI - 1);
    int bcix = gid >> 9;
    int c = bcix & (CH - 1);
    int bl = bcix >> 6;
    float A[DS], h[DS];
    #pragma unroll
    for (int n = 0; n < DS; n++) { A[n] = -__expf(Alog[d * DS + n]); h[n] = 0.f; }
    int tbase = c * CLEN;
    const float* dtp = dt + ((size_t)bl * T_LR + tbase) * DI + d;
    const float* xp  = x  + ((size_t)bl * T_LR + tbase) * DI + d;
    const float* bcp = dbc + ((size_t)bl * T_LR + tbase) * DBC_W;
    float S = 0.f;
    for (int t = 0; t < CLEN; t++) {
        float dtv = dtp[(size_t)t * DI];
        float xv  = xp[(size_t)t * DI];
        float dtx = dtv * xv;
        const float* bc = bcp + (size_t)t * DBC_W;
        S += dtv;
        #pragma unroll
        for (int n = 0; n < DS; n++)
            h[n] = __expf(dtv * A[n]) * h[n] + dtx * bc[16 + n];
    }
    float* hp = hS + (size_t)gid * DS;
    #pragma unroll
    for (int n = 0; n < DS; n++) hp[n] = h[n];
    csum[gid] = S;
}

// ---------------------------------------------------------------------------
// scan phase 2: per (bl, d, n) thread; sequential over CH chunks.
// Converts chunk-local end states (hS) into chunk-start states, in place.
// ---------------------------------------------------------------------------
__global__ __launch_bounds__(256) void k_scan_p2(float* __restrict__ hS,
                                                 const float* __restrict__ csum,
                                                 const float* __restrict__ Alog) {
    int gid = blockIdx.x * 256 + threadIdx.x;   // (bl*DI + d)*DS + n
    int n = gid & (DS - 1);
    int d = (gid >> 4) & (DI - 1);
    int bl = gid >> 13;
    float An = -__expf(Alog[d * DS + n]);
    float hs = 0.f;
    for (int c = 0; c < CH; c++) {
        size_t base = ((size_t)(bl * CH + c) * DI + d);
        float he = hS[base * DS + n];
        float S  = csum[base];
        hS[base * DS + n] = hs;
        hs = __expf(An * S) * hs + he;
    }
}

// ---------------------------------------------------------------------------
// scan phase 3: per (bl, chunk, d) thread, starts from corrected chunk-start
// state, emits y in place over x (per-thread column, safe).
// ---------------------------------------------------------------------------
__global__ __launch_bounds__(256) void k_scan_p3(const float* __restrict__ dt,
                                                 float* x,   // in: xcs, out: y (in place)
                                                 const float* __restrict__ dbc,
                                                 const float* __restrict__ Alog,
                                                 const float* __restrict__ Dp,
                                                 const float* __restrict__ hS) {
    int gid = blockIdx.x * 256 + threadIdx.x;   // (bl*CH + c)*DI + d
    int d = gid & (DI - 1);
    int bcix = gid >> 9;
    int c = bcix & (CH - 1);
    int bl = bcix >> 6;
    float A[DS], h[DS];
    const float* hp = hS + (size_t)gid * DS;
    #pragma unroll
    for (int n = 0; n < DS; n++) { A[n] = -__expf(Alog[d * DS + n]); h[n] = hp[n]; }
    float Dd = Dp[d];
    int tbase = c * CLEN;
    const float* dtp = dt + ((size_t)bl * T_LR + tbase) * DI + d;
    float* xp  = x  + ((size_t)bl * T_LR + tbase) * DI + d;
    const float* bcp = dbc + ((size_t)bl * T_LR + tbase) * DBC_W;
    for (int t = 0; t < CLEN; t++) {
        float dtv = dtp[(size_t)t * DI];
        float xv  = xp[(size_t)t * DI];
        float dtx = dtv * xv;
        const float* bc = bcp + (size_t)t * DBC_W;
        float acc = 0.f;
        #pragma unroll
        for (int n = 0; n < DS; n++) {
            h[n] = __expf(dtv * A[n]) * h[n] + dtx * bc[16 + n];
            acc += h[n] * bc[32 + n];
        }
        xp[(size_t)t * DI] = acc + xv * Dd;
    }
}

// ---------------------------------------------------------------------------
// convd (512ch -> 256ch, k=3 same) + batchnorm + silu.
// ---------------------------------------------------------------------------
__global__ __launch_bounds__(256) void k_convd(const float* __restrict__ comb,
                                               const float* __restrict__ tb,
                                               const float* __restrict__ w,
                                               const float* __restrict__ bias,
                                               const float* __restrict__ bng,
                                               const float* __restrict__ bnb,
                                               const float* __restrict__ bnm,
                                               const float* __restrict__ bnv,
                                               float* __restrict__ out) {
    int b = blockIdx.y;
    int t0 = blockIdx.x * 16;
    int co = threadIdx.x;
    __shared__ float s[64][18];
    float acc[16] = {};
    const float* wp = w + (size_t)co * 512 * 3;
    for (int cc = 0; cc < 8; cc++) {
        __syncthreads();
        for (int i = threadIdx.x; i < 64 * 18; i += 256) {
            int ci_l = i & 63, dtt = i >> 6;
            int ci = cc * 64 + ci_l;
            int t = t0 - 1 + dtt;
            float v = 0.f;
            if (t >= 0 && t < T_LR)
                v = (ci < 256) ? comb[((size_t)b * T_LR + t) * DM + ci]
                               : tb[((size_t)b * T_LR + t) * DM + ci - 256];
            s[ci_l][dtt] = v;
        }
        __syncthreads();
        for (int ci_l = 0; ci_l < 64; ci_l++) {
            int ci = cc * 64 + ci_l;
            float w0 = wp[ci * 3], w1 = wp[ci * 3 + 1], w2 = wp[ci * 3 + 2];
            #pragma unroll
            for (int tt = 0; tt < 16; tt++)
                acc[tt] += s[ci_l][tt] * w0 + s[ci_l][tt + 1] * w1 + s[ci_l][tt + 2] * w2;
        }
    }
    float scale = rsqrtf(bnv[co] + 1e-5f) * bng[co];
    float shift = bnb[co] - bnm[co] * scale;
    float bi = bias[co];
    #pragma unroll
    for (int tt = 0; tt < 16; tt++) {
        float v = (acc[tt] + bi) * scale + shift;
        out[((size_t)b * T_LR + t0 + tt) * DM + co] = silu_f(v);
    }
}

// ---------------------------------------------------------------------------
// sp conv (256ch -> 128ch, k=3 same) + pixel shuffle (R=2) -> d_out
// ---------------------------------------------------------------------------
__global__ __launch_bounds__(128) void k_sp(const float* __restrict__ din,
                                            const float* __restrict__ w,
                                            const float* __restrict__ bias,
                                            float* __restrict__ out) {
    int b = blockIdx.y;
    int t0 = blockIdx.x * 16;
    int c = threadIdx.x;    // 0..127
    __shared__ float s[64][18];
    float acc[16];
    float bi = bias[c];
    #pragma unroll
    for (int tt = 0; tt < 16; tt++) acc[tt] = bi;
    const float* wp = w + (size_t)c * 256 * 3;
    for (int cc = 0; cc < 4; cc++) {
        __syncthreads();
        for (int i = threadIdx.x; i < 64 * 18; i += 128) {
            int ci_l = i & 63, dtt = i >> 6;
            int ci = cc * 64 + ci_l;
            int t = t0 - 1 + dtt;
            float v = 0.f;
            if (t >= 0 && t < T_LR) v = din[((size_t)b * T_LR + t) * DM + ci];
            s[ci_l][dtt] = v;
        }
        __syncthreads();
        for (int ci_l = 0; ci_l < 64; ci_l++) {
            int ci = cc * 64 + ci_l;
            float w0 = wp[ci * 3], w1 = wp[ci * 3 + 1], w2 = wp[ci * 3 + 2];
            #pragma unroll
            for (int tt = 0; tt < 16; tt++)
                acc[tt] += s[ci_l][tt] * w0 + s[ci_l][tt + 1] * w1 + s[ci_l][tt + 2] * w2;
        }
    }
    int c2 = c >> 1, r = c & 1;
    #pragma unroll
    for (int tt = 0; tt < 16; tt++) {
        size_t oi = (((size_t)b * 64 + c2) * T_LR + t0 + tt) * 2 + r;
        out[oi] = acc[tt];
    }
}

// ---------------------------------------------------------------------------
extern "C" void kernel_launch(void* const* d_in, const int* in_sizes, int n_in,
                              void* d_out, int out_size, void* d_ws, size_t ws_size,
                              hipStream_t stream) {
    const float* x       = (const float*)d_in[0];
    const float* enc_w1  = (const float*)d_in[1];
    const float* enc_b1  = (const float*)d_in[2];
    const float* enc_w2  = (const float*)d_in[3];
    const float* enc_b2  = (const float*)d_in[4];
    const float* norm1_w = (const float*)d_in[5];
    const float* norm2_w = (const float*)d_in[6];
    const float* convd_w = (const float*)d_in[25];
    const float* convd_b = (const float*)d_in[26];
    const float* bn_g    = (const float*)d_in[27];
    const float* bn_b    = (const float*)d_in[28];
    const float* bn_mean = (const float*)d_in[29];
    const float* bn_var  = (const float*)d_in[30];
    const float* sp_w    = (const float*)d_in[31];
    const float* sp_b    = (const float*)d_in[32];
    float* out = (float*)d_out;

    // ---- workspace layout (floats) ----
    // persistent: t_buf, xn_buf, mo (each BT*DM)
    // scratch per Bc batches: P1 (Tc*DI) | P2 (Tc*DI) | db (Tc*DBC_W)
    //                       | hS (Bc*CH*DI*DS) | csum (Bc*CH*DI)
    float* ws = (float*)d_ws;
    size_t availf = ws_size / sizeof(float);
    float* t_buf  = ws;
    float* xn_buf = ws + (size_t)BT * DM;
    float* mo     = ws + 2 * (size_t)BT * DM;
    float* scratch = ws + 3 * (size_t)BT * DM;
    size_t persist = 3 * (size_t)BT * DM;
    size_t scratch_avail = (availf > persist) ? (availf - persist) : 0;
    size_t per_b = (size_t)T_LR * (2 * DI + DBC_W) + (size_t)CH * DI * (DS + 1);
    int Bc = 16;
    while (Bc > 1 && (size_t)Bc * per_b > scratch_avail) Bc >>= 1;

    float* e1 = mo;   // 16*128*2560 = 5.24M floats fits in mo (10.49M); dead before out_proj

    // encoder
    k_enc1<<<(B_SZ * 128 * T_LR) / 256, 256, 0, stream>>>(x, enc_w1, enc_b1, e1);
    k_enc2<<<dim3(T_LR / 16, B_SZ), 256, 0, stream>>>(e1, enc_w2, enc_b2, t_buf);
    k_rmsnorm<<<BT / 4, 256, 0, stream>>>(t_buf, norm1_w, xn_buf, BT);

    for (int dir = 0; dir < 2; dir++) {
        const float* inW   = (const float*)d_in[7 + 9 * dir];
        const float* convW = (const float*)d_in[8 + 9 * dir];
        const float* convb = (const float*)d_in[9 + 9 * dir];
        const float* xW    = (const float*)d_in[10 + 9 * dir];
        const float* dtW   = (const float*)d_in[11 + 9 * dir];
        const float* dtb   = (const float*)d_in[12 + 9 * dir];
        const float* Alog  = (const float*)d_in[13 + 9 * dir];
        const float* Dp    = (const float*)d_in[14 + 9 * dir];
        const float* outW  = (const float*)d_in[15 + 9 * dir];
        int rev = dir;
        for (int b0 = 0; b0 < B_SZ; b0 += Bc) {
            int Tc = Bc * T_LR;
            float* P1  = scratch;
            float* P2  = scratch + (size_t)Tc * DI;
            float* db  = scratch + 2 * (size_t)Tc * DI;
            float* hS  = db + (size_t)Tc * DBC_W;
            float* csum = hS + (size_t)Bc * CH * DI * DS;
            const float* xnC = xn_buf + (size_t)b0 * T_LR * DM;
            float*       moC = mo     + (size_t)b0 * T_LR * DM;
            // xc_pre = xn(rev) @ inW[0:512]^T  -> P1
            k_gemm<<<dim3(Tc / 64, 8), 256, 0, stream>>>(xnC, DM, nullptr, inW, P1, DI,
                                                         nullptr, nullptr, DI, DM, 0, rev, 0, 0);
            // depthwise causal conv + silu -> P2 (xcs)
            k_dwconv<<<((size_t)Tc * DI) / 256, 256, 0, stream>>>(P1, convW, convb, P2);
            // dbc = xcs @ xW^T -> db
            k_gemm<<<dim3(Tc / 64, 1), 256, 0, stream>>>(P2, DI, nullptr, xW, db, DBC_W,
                                                         nullptr, nullptr, DBC_W, DI, 0, 0, 0, 0);
            // dt = softplus(dbc[:, :16] @ dtW^T + dtb) -> P1 (xc_pre dead)
            k_gemm<<<dim3(Tc / 64, 8), 256, 0, stream>>>(db, DBC_W, nullptr, dtW, P1, DI,
                                                         dtb, nullptr, DI, DTR, 2, 0, 0, 0);
            // chunked selective scan (3 phases); y written in place over P2
            k_scan_p1<<<(Bc * CH * DI) / 256, 256, 0, stream>>>(P1, P2, db, Alog, hS, csum);
            k_scan_p2<<<(Bc * DI * DS) / 256, 256, 0, stream>>>(hS, csum, Alog);
            k_scan_p3<<<(Bc * CH * DI) / 256, 256, 0, stream>>>(P1, P2, db, Alog, Dp, hS);
            // z = xn(rev) @ inW[512:1024]^T -> P1 (dt dead)
            k_gemm<<<dim3(Tc / 64, 8), 256, 0, stream>>>(xnC, DM, nullptr, inW + (size_t)DI * DM, P1, DI,
                                                         nullptr, nullptr, DI, DM, 0, rev, 0, 0);
            // mo (+)= (y * silu(z)) @ outW^T + xn   (crev for backward direction)
            k_gemm<<<dim3(Tc / 64, 4), 256, 0, stream>>>(P2, DI, P1, outW, moC, DM,
                                                         nullptr, xnC, DM, DI, 0, 0, rev, dir);
        }
    }

    // combined = rmsnorm(mo) -> comb (reuses xn_buf, now dead)
    float* comb = xn_buf;
    k_rmsnorm<<<BT / 4, 256, 0, stream>>>(mo, norm2_w, comb, BT);
    // convd + bn + silu -> d_buf (reuses mo, now dead)
    float* d_buf = mo;
    k_convd<<<dim3(T_LR / 16, B_SZ), 256, 0, stream>>>(comb, t_buf, convd_w, convd_b,
                                                       bn_g, bn_b, bn_mean, bn_var, d_buf);
    // sp conv + pixel shuffle -> out
    k_sp<<<dim3(T_LR / 16, B_SZ), 128, 0, stream>>>(d_buf, sp_w, sp_b, out);
}

// Round 4
// 3902.574 us; speedup vs baseline: 2.6324x; 1.0049x over previous
//
#include <hip/hip_runtime.h>
#include <hip/hip_bf16.h>
#include <math.h>

#define B_SZ 16
#define T_LR 2560
#define BT (B_SZ * T_LR)     // 40960 tokens
#define DM 256               // d_model
#define DI 512               // d_inner
#define DS 16                // d_state
#define DTR 16               // dt_rank
#define DBC_W 48             // dt_rank + 2*d_state
#define CH 64                // scan chunks per sequence
#define CLEN (T_LR / CH)     // 40 steps per chunk

typedef __attribute__((ext_vector_type(8))) short bf16x8;
typedef __attribute__((ext_vector_type(4))) float f32x4;

__device__ __forceinline__ float silu_f(float x) {
    return x / (1.f + __expf(-x));
}
__device__ __forceinline__ unsigned short f2bf(float v) {
    __hip_bfloat16 h = __float2bfloat16(v);
    return *(unsigned short*)&h;
}
__device__ __forceinline__ int seqrev(int r) {
    int s = r / T_LR, t = r % T_LR;
    return s * T_LR + (T_LR - 1 - t);
}

// ---------------------------------------------------------------------------
// enc conv1: x(16,64,2560) -> e1(16,128,2560), k=3 same pad, silu
// ---------------------------------------------------------------------------
__global__ __launch_bounds__(256) void k_enc1(const float* __restrict__ x,
                                              const float* __restrict__ w,
                                              const float* __restrict__ bias,
                                              float* __restrict__ out) {
    int idx = blockIdx.x * 256 + threadIdx.x;       // b*128*2560
    int t = idx % T_LR;
    int c = (idx / T_LR) & 127;
    int b = idx / (T_LR * 128);
    float acc = bias[c];
    const float* wp = w + c * 64 * 3;
    const float* xp = x + (size_t)b * 64 * T_LR + t;
    #pragma unroll 4
    for (int ci = 0; ci < 64; ci++) {
        float w0 = wp[ci * 3 + 0], w1 = wp[ci * 3 + 1], w2 = wp[ci * 3 + 2];
        const float* xr = xp + (size_t)ci * T_LR;
        if (t > 0) acc += xr[-1] * w0;
        acc += xr[0] * w1;
        if (t < T_LR - 1) acc += xr[1] * w2;
    }
    out[idx] = silu_f(acc);
}

// ---------------------------------------------------------------------------
// enc conv2: e1(16,128,2560) -> t_buf(16,2560,256) [transposed!], silu
// ---------------------------------------------------------------------------
__global__ __launch_bounds__(256) void k_enc2(const float* __restrict__ e1,
                                              const float* __restrict__ w,
                                              const float* __restrict__ bias,
                                              float* __restrict__ out) {
    int b = blockIdx.y;
    int t0 = blockIdx.x * 16;
    int co = threadIdx.x;
    __shared__ float s[128][19];
    for (int i = threadIdx.x; i < 128 * 18; i += 256) {
        int ci = i / 18, dtt = i % 18;
        int t = t0 - 1 + dtt;
        s[ci][dtt] = (t >= 0 && t < T_LR) ? e1[((size_t)b * 128 + ci) * T_LR + t] : 0.f;
    }
    __syncthreads();
    float acc[16];
    float bi = bias[co];
    #pragma unroll
    for (int tt = 0; tt < 16; tt++) acc[tt] = bi;
    const float* wp = w + (size_t)co * 128 * 3;
    for (int ci = 0; ci < 128; ci++) {
        float w0 = wp[ci * 3], w1 = wp[ci * 3 + 1], w2 = wp[ci * 3 + 2];
        #pragma unroll
        for (int tt = 0; tt < 16; tt++)
            acc[tt] += s[ci][tt] * w0 + s[ci][tt + 1] * w1 + s[ci][tt + 2] * w2;
    }
    #pragma unroll
    for (int tt = 0; tt < 16; tt++)
        out[((size_t)b * T_LR + t0 + tt) * DM + co] = silu_f(acc[tt]);
}

// ---------------------------------------------------------------------------
// rmsnorm over last dim (256). One wave per token. Optional bf16 mirror out.
// ---------------------------------------------------------------------------
__global__ __launch_bounds__(256) void k_rmsnorm(const float* __restrict__ in1,
                                                 const float* __restrict__ w,
                                                 float* __restrict__ out,
                                                 unsigned short* __restrict__ out_bf,
                                                 int ntok) {
    int tok = (blockIdx.x * 256 + threadIdx.x) >> 6;
    int lane = threadIdx.x & 63;
    if (tok >= ntok) return;
    float4 v = ((const float4*)(in1 + (size_t)tok * DM))[lane];
    float ss = v.x * v.x + v.y * v.y + v.z * v.z + v.w * v.w;
    #pragma unroll
    for (int off = 32; off > 0; off >>= 1) ss += __shfl_xor(ss, off);
    float sc = rsqrtf(ss * (1.f / 256.f) + 1e-6f);
    float4 wv = ((const float4*)w)[lane];
    float4 o;
    o.x = v.x * sc * wv.x; o.y = v.y * sc * wv.y;
    o.z = v.z * sc * wv.z; o.w = v.w * sc * wv.w;
    ((float4*)(out + (size_t)tok * DM))[lane] = o;
    if (out_bf) {
        ushort4 ob;
        ob.x = f2bf(o.x); ob.y = f2bf(o.y); ob.z = f2bf(o.z); ob.w = f2bf(o.w);
        ((ushort4*)(out_bf + (size_t)tok * DM))[lane] = ob;
    }
}

// ---------------------------------------------------------------------------
// f32 -> bf16 cast (weights)
// ---------------------------------------------------------------------------
__global__ __launch_bounds__(256) void k_cast(const float* __restrict__ in,
                                              unsigned short* __restrict__ out, int n) {
    int i = blockIdx.x * 256 + threadIdx.x;
    if (i < n) out[i] = f2bf(in[i]);
}

// ---------------------------------------------------------------------------
// gate + cast: yg = bf16(y * silu(z))
// ---------------------------------------------------------------------------
__global__ __launch_bounds__(256) void k_gate_bf(const float* __restrict__ y,
                                                 const float* __restrict__ z,
                                                 unsigned short* __restrict__ yg) {
    int i = blockIdx.x * 256 + threadIdx.x;
    yg[i] = f2bf(y[i] * silu_f(z[i]));
}

// ---------------------------------------------------------------------------
// bf16 MFMA GEMM: C[M,N](f32) = A[M,K](bf16) @ Bw[N,K](bf16)^T (+res)(+C accum)
// 128x128 tile, 256 threads = 4 waves, each wave 64x64 via 4x4 mfma 16x16x32.
// arev: A rows read time-reversed within T_LR segments; crev: C/res rows reversed.
// M % 128 == 0, N % 128 == 0, K % 32 == 0.
// ---------------------------------------------------------------------------
__global__ __launch_bounds__(256) void k_gemm_bf(const unsigned short* __restrict__ A, int lda,
                                                 const unsigned short* __restrict__ Bw,
                                                 float* C, int ldc,
                                                 const float* __restrict__ res,
                                                 int K, int arev, int crev, int accum) {
    __shared__ unsigned short As[128][40];
    __shared__ unsigned short Bs[128][40];
    int tid = threadIdx.x;
    int wave = tid >> 6, lane = tid & 63;
    int wm = (wave >> 1) * 64, wn = (wave & 1) * 64;
    int m0 = blockIdx.x * 128, n0 = blockIdx.y * 128;
    int sc = tid & 3;         // col group (8 cols each)
    int sr = tid >> 2;        // rows sr and sr+64
    int ar0 = m0 + sr, ar1 = m0 + sr + 64;
    if (arev) { ar0 = seqrev(ar0); ar1 = seqrev(ar1); }
    const unsigned short* ap0 = A + (size_t)ar0 * lda + sc * 8;
    const unsigned short* ap1 = A + (size_t)ar1 * lda + sc * 8;
    const unsigned short* bp0 = Bw + (size_t)(n0 + sr) * K + sc * 8;
    const unsigned short* bp1 = Bw + (size_t)(n0 + sr + 64) * K + sc * 8;
    f32x4 acc[4][4] = {};
    int q = lane >> 4, ml = lane & 15;
    for (int k0 = 0; k0 < K; k0 += 32) {
        uint4 a0 = *(const uint4*)(ap0 + k0);
        uint4 a1 = *(const uint4*)(ap1 + k0);
        uint4 b0 = *(const uint4*)(bp0 + k0);
        uint4 b1 = *(const uint4*)(bp1 + k0);
        __syncthreads();
        *(uint4*)&As[sr][sc * 8]      = a0;
        *(uint4*)&As[sr + 64][sc * 8] = a1;
        *(uint4*)&Bs[sr][sc * 8]      = b0;
        *(uint4*)&Bs[sr + 64][sc * 8] = b1;
        __syncthreads();
        bf16x8 af[4], bfr[4];
        #pragma unroll
        for (int mi = 0; mi < 4; mi++)
            af[mi] = *(const bf16x8*)&As[wm + mi * 16 + ml][q * 8];
        #pragma unroll
        for (int ni = 0; ni < 4; ni++)
            bfr[ni] = *(const bf16x8*)&Bs[wn + ni * 16 + ml][q * 8];
        #pragma unroll
        for (int mi = 0; mi < 4; mi++)
            #pragma unroll
            for (int ni = 0; ni < 4; ni++)
                acc[mi][ni] = __builtin_amdgcn_mfma_f32_16x16x32_bf16(af[mi], bfr[ni], acc[mi][ni], 0, 0, 0);
    }
    #pragma unroll
    for (int mi = 0; mi < 4; mi++) {
        #pragma unroll
        for (int r = 0; r < 4; r++) {
            int mr = m0 + wm + mi * 16 + q * 4 + r;
            int orow = crev ? seqrev(mr) : mr;
            float* crow = C + (size_t)orow * ldc;
            const float* rrow = res ? res + (size_t)orow * ldc : nullptr;
            #pragma unroll
            for (int ni = 0; ni < 4; ni++) {
                int col = n0 + wn + ni * 16 + ml;
                float v = acc[mi][ni][r];
                if (res) v += rrow[col];
                if (accum) v += crow[col];
                crow[col] = v;
            }
        }
    }
}

// ---------------------------------------------------------------------------
// generic tiled fp32 GEMM (still used for x_proj N=48 and dt K=16)
// ---------------------------------------------------------------------------
__global__ __launch_bounds__(256) void k_gemm(const float* __restrict__ A, int lda,
                                              const float* __restrict__ Bw,
                                              float* C, int ldc,
                                              const float* __restrict__ bias,
                                              int N, int K, int act) {
    __shared__ float As[16][68];
    __shared__ float Bs[16][68];
    int bm = blockIdx.x, bn = blockIdx.y;
    int tid = threadIdx.x;
    int tx = tid & 15, ty = tid >> 4;
    int lm = tid & 63, kq = tid >> 6;
    float acc[4][4] = {};
    int arow = bm * 64 + lm;
    int brow = bn * 64 + lm;
    const float4* ap = (const float4*)(A + (size_t)arow * lda) + kq;
    bool bvalid = brow < N;
    const float4* bp = (const float4*)(Bw + (size_t)brow * K) + kq;
    for (int k0 = 0; k0 < K; k0 += 16) {
        float4 av = ap[0]; ap += 4;
        float4 bv = make_float4(0.f, 0.f, 0.f, 0.f);
        if (bvalid) { bv = bp[0]; bp += 4; }
        As[kq * 4 + 0][lm] = av.x; As[kq * 4 + 1][lm] = av.y;
        As[kq * 4 + 2][lm] = av.z; As[kq * 4 + 3][lm] = av.w;
        Bs[kq * 4 + 0][lm] = bv.x; Bs[kq * 4 + 1][lm] = bv.y;
        Bs[kq * 4 + 2][lm] = bv.z; Bs[kq * 4 + 3][lm] = bv.w;
        __syncthreads();
        #pragma unroll
        for (int kk = 0; kk < 16; kk++) {
            float4 a = *(const float4*)&As[kk][ty * 4];
            float4 b = *(const float4*)&Bs[kk][tx * 4];
            acc[0][0] += a.x * b.x; acc[0][1] += a.x * b.y; acc[0][2] += a.x * b.z; acc[0][3] += a.x * b.w;
            acc[1][0] += a.y * b.x; acc[1][1] += a.y * b.y; acc[1][2] += a.y * b.z; acc[1][3] += a.y * b.w;
            acc[2][0] += a.z * b.x; acc[2][1] += a.z * b.y; acc[2][2] += a.z * b.z; acc[2][3] += a.z * b.w;
            acc[3][0] += a.w * b.x; acc[3][1] += a.w * b.y; acc[3][2] += a.w * b.z; acc[3][3] += a.w * b.w;
        }
        __syncthreads();
    }
    #pragma unroll
    for (int i = 0; i < 4; i++) {
        int mr = bm * 64 + ty * 4 + i;
        #pragma unroll
        for (int j = 0; j < 4; j++) {
            int n = bn * 64 + tx * 4 + j;
            if (n < N) {
                float v = acc[i][j];
                if (bias) v += bias[n];
                if (act == 2) v = (v > 20.f) ? v : log1pf(__expf(v));
                C[(size_t)mr * ldc + n] = v;
            }
        }
    }
}

// ---------------------------------------------------------------------------
// depthwise causal conv k=4 + bias + silu.  xc (Tc,512) -> out (Tc,512)
// ---------------------------------------------------------------------------
__global__ __launch_bounds__(256) void k_dwconv(const float* __restrict__ xc,
                                                const float* __restrict__ cw,
                                                const float* __restrict__ cb,
                                                float* __restrict__ out) {
    int idx = blockIdx.x * 256 + threadIdx.x;   // Tc*512
    int d = idx & (DI - 1);
    int row = idx >> 9;
    int t = row % T_LR;
    float acc = cb[d];
    #pragma unroll
    for (int k = 0; k < 4; k++) {
        int tt = t - 3 + k;
        if (tt >= 0) acc += xc[(size_t)(row - t + tt) * DI + d] * cw[d * 4 + k];
    }
    out[idx] = silu_f(acc);
}

// ---------------------------------------------------------------------------
// scan phase 1: per (bl, chunk, d) thread. Chunk-local scan from h=0.
// ---------------------------------------------------------------------------
__global__ __launch_bounds__(256) void k_scan_p1(const float* __restrict__ dt,
                                                 const float* __restrict__ x,
                                                 const float* __restrict__ dbc,
                                                 const float* __restrict__ Alog,
                                                 float* __restrict__ hS,
                                                 float* __restrict__ csum) {
    int gid = blockIdx.x * 256 + threadIdx.x;   // (bl*CH + c)*DI + d
    int d = gid & (DI - 1);
    int bcix = gid >> 9;
    int c = bcix & (CH - 1);
    int bl = bcix >> 6;
    float A[DS], h[DS];
    #pragma unroll
    for (int n = 0; n < DS; n++) { A[n] = -__expf(Alog[d * DS + n]); h[n] = 0.f; }
    int tbase = c * CLEN;
    const float* dtp = dt + ((size_t)bl * T_LR + tbase) * DI + d;
    const float* xp  = x  + ((size_t)bl * T_LR + tbase) * DI + d;
    const float* bcp = dbc + ((size_t)bl * T_LR + tbase) * DBC_W;
    float S = 0.f;
    for (int t = 0; t < CLEN; t++) {
        float dtv = dtp[(size_t)t * DI];
        float xv  = xp[(size_t)t * DI];
        float dtx = dtv * xv;
        const float* bc = bcp + (size_t)t * DBC_W;
        S += dtv;
        #pragma unroll
        for (int n = 0; n < DS; n++)
            h[n] = __expf(dtv * A[n]) * h[n] + dtx * bc[16 + n];
    }
    float* hp = hS + (size_t)gid * DS;
    #pragma unroll
    for (int n = 0; n < DS; n++) hp[n] = h[n];
    csum[gid] = S;
}

// ---------------------------------------------------------------------------
// scan phase 2: per (bl, d, n) thread; sequential over CH chunks, in place.
// ---------------------------------------------------------------------------
__global__ __launch_bounds__(256) void k_scan_p2(float* __restrict__ hS,
                                                 const float* __restrict__ csum,
                                                 const float* __restrict__ Alog) {
    int gid = blockIdx.x * 256 + threadIdx.x;   // (bl*DI + d)*DS + n
    int n = gid & (DS - 1);
    int d = (gid >> 4) & (DI - 1);
    int bl = gid >> 13;
    float An = -__expf(Alog[d * DS + n]);
    float hs = 0.f;
    for (int c = 0; c < CH; c++) {
        size_t base = ((size_t)(bl * CH + c) * DI + d);
        float he = hS[base * DS + n];
        float S  = csum[base];
        hS[base * DS + n] = hs;
        hs = __expf(An * S) * hs + he;
    }
}

// ---------------------------------------------------------------------------
// scan phase 3: corrected chunk-start state, emits y in place over x.
// ---------------------------------------------------------------------------
__global__ __launch_bounds__(256) void k_scan_p3(const float* __restrict__ dt,
                                                 float* x,
                                                 const float* __restrict__ dbc,
                                                 const float* __restrict__ Alog,
                                                 const float* __restrict__ Dp,
                                                 const float* __restrict__ hS) {
    int gid = blockIdx.x * 256 + threadIdx.x;   // (bl*CH + c)*DI + d
    int d = gid & (DI - 1);
    int bcix = gid >> 9;
    int c = bcix & (CH - 1);
    int bl = bcix >> 6;
    float A[DS], h[DS];
    const float* hp = hS + (size_t)gid * DS;
    #pragma unroll
    for (int n = 0; n < DS; n++) { A[n] = -__expf(Alog[d * DS + n]); h[n] = hp[n]; }
    float Dd = Dp[d];
    int tbase = c * CLEN;
    const float* dtp = dt + ((size_t)bl * T_LR + tbase) * DI + d;
    float* xp  = x  + ((size_t)bl * T_LR + tbase) * DI + d;
    const float* bcp = dbc + ((size_t)bl * T_LR + tbase) * DBC_W;
    for (int t = 0; t < CLEN; t++) {
        float dtv = dtp[(size_t)t * DI];
        float xv  = xp[(size_t)t * DI];
        float dtx = dtv * xv;
        const float* bc = bcp + (size_t)t * DBC_W;
        float acc = 0.f;
        #pragma unroll
        for (int n = 0; n < DS; n++) {
            h[n] = __expf(dtv * A[n]) * h[n] + dtx * bc[16 + n];
            acc += h[n] * bc[32 + n];
        }
        xp[(size_t)t * DI] = acc + xv * Dd;
    }
}

// ---------------------------------------------------------------------------
// convd (512ch -> 256ch, k=3 same) + batchnorm + silu.
// ---------------------------------------------------------------------------
__global__ __launch_bounds__(256) void k_convd(const float* __restrict__ comb,
                                               const float* __restrict__ tb,
                                               const float* __restrict__ w,
                                               const float* __restrict__ bias,
                                               const float* __restrict__ bng,
                                               const float* __restrict__ bnb,
                                               const float* __restrict__ bnm,
                                               const float* __restrict__ bnv,
                                               float* __restrict__ out) {
    int b = blockIdx.y;
    int t0 = blockIdx.x * 16;
    int co = threadIdx.x;
    __shared__ float s[64][19];
    float acc[16] = {};
    const float* wp = w + (size_t)co * 512 * 3;
    for (int cc = 0; cc < 8; cc++) {
        __syncthreads();
        for (int i = threadIdx.x; i < 64 * 18; i += 256) {
            int ci_l = i & 63, dtt = i >> 6;
            int ci = cc * 64 + ci_l;
            int t = t0 - 1 + dtt;
            float v = 0.f;
            if (t >= 0 && t < T_LR)
                v = (ci < 256) ? comb[((size_t)b * T_LR + t) * DM + ci]
                               : tb[((size_t)b * T_LR + t) * DM + ci - 256];
            s[ci_l][dtt] = v;
        }
        __syncthreads();
        for (int ci_l = 0; ci_l < 64; ci_l++) {
            int ci = cc * 64 + ci_l;
            float w0 = wp[ci * 3], w1 = wp[ci * 3 + 1], w2 = wp[ci * 3 + 2];
            #pragma unroll
            for (int tt = 0; tt < 16; tt++)
                acc[tt] += s[ci_l][tt] * w0 + s[ci_l][tt + 1] * w1 + s[ci_l][tt + 2] * w2;
        }
    }
    float scale = rsqrtf(bnv[co] + 1e-5f) * bng[co];
    float shift = bnb[co] - bnm[co] * scale;
    float bi = bias[co];
    #pragma unroll
    for (int tt = 0; tt < 16; tt++) {
        float v = (acc[tt] + bi) * scale + shift;
        out[((size_t)b * T_LR + t0 + tt) * DM + co] = silu_f(v);
    }
}

// ---------------------------------------------------------------------------
// sp conv (256ch -> 128ch, k=3 same) + pixel shuffle (R=2) -> d_out
// ---------------------------------------------------------------------------
__global__ __launch_bounds__(128) void k_sp(const float* __restrict__ din,
                                            const float* __restrict__ w,
                                            const float* __restrict__ bias,
                                            float* __restrict__ out) {
    int b = blockIdx.y;
    int t0 = blockIdx.x * 16;
    int c = threadIdx.x;    // 0..127
    __shared__ float s[64][19];
    float acc[16];
    float bi = bias[c];
    #pragma unroll
    for (int tt = 0; tt < 16; tt++) acc[tt] = bi;
    const float* wp = w + (size_t)c * 256 * 3;
    for (int cc = 0; cc < 4; cc++) {
        __syncthreads();
        for (int i = threadIdx.x; i < 64 * 18; i += 128) {
            int ci_l = i & 63, dtt = i >> 6;
            int ci = cc * 64 + ci_l;
            int t = t0 - 1 + dtt;
            float v = 0.f;
            if (t >= 0 && t < T_LR) v = din[((size_t)b * T_LR + t) * DM + ci];
            s[ci_l][dtt] = v;
        }
        __syncthreads();
        for (int ci_l = 0; ci_l < 64; ci_l++) {
            int ci = cc * 64 + ci_l;
            float w0 = wp[ci * 3], w1 = wp[ci * 3 + 1], w2 = wp[ci * 3 + 2];
            #pragma unroll
            for (int tt = 0; tt < 16; tt++)
                acc[tt] += s[ci_l][tt] * w0 + s[ci_l][tt + 1] * w1 + s[ci_l][tt + 2] * w2;
        }
    }
    int c2 = c >> 1, r = c & 1;
    #pragma unroll
    for (int tt = 0; tt < 16; tt++) {
        size_t oi = (((size_t)b * 64 + c2) * T_LR + t0 + tt) * 2 + r;
        out[oi] = acc[tt];
    }
}

// ---------------------------------------------------------------------------
extern "C" void kernel_launch(void* const* d_in, const int* in_sizes, int n_in,
                              void* d_out, int out_size, void* d_ws, size_t ws_size,
                              hipStream_t stream) {
    const float* x       = (const float*)d_in[0];
    const float* enc_w1  = (const float*)d_in[1];
    const float* enc_b1  = (const float*)d_in[2];
    const float* enc_w2  = (const float*)d_in[3];
    const float* enc_b2  = (const float*)d_in[4];
    const float* norm1_w = (const float*)d_in[5];
    const float* norm2_w = (const float*)d_in[6];
    const float* convd_w = (const float*)d_in[25];
    const float* convd_b = (const float*)d_in[26];
    const float* bn_g    = (const float*)d_in[27];
    const float* bn_b    = (const float*)d_in[28];
    const float* bn_mean = (const float*)d_in[29];
    const float* bn_var  = (const float*)d_in[30];
    const float* sp_w    = (const float*)d_in[31];
    const float* sp_b    = (const float*)d_in[32];
    float* out = (float*)d_out;

    // ---- workspace layout (float slots) ----
    float* ws = (float*)d_ws;
    size_t availf = ws_size / sizeof(float);
    float* t_buf  = ws;
    float* xn_buf = ws + (size_t)BT * DM;
    float* mo     = ws + 2 * (size_t)BT * DM;
    unsigned short* xn_bf = (unsigned short*)(ws + 3 * (size_t)BT * DM);   // BT*DM bf16 = BT*DM/2 slots
    unsigned short* inW_bf  = (unsigned short*)(ws + 3 * (size_t)BT * DM + (size_t)BT * DM / 2);
    unsigned short* outW_bf = inW_bf + 1024 * DM;                           // 262144 ushorts
    size_t persist = 3 * (size_t)BT * DM + (size_t)BT * DM / 2 + (262144 + 131072 + 2) / 2;
    float* scratch = ws + persist;
    size_t scratch_avail = (availf > persist) ? (availf - persist) : 0;
    // per-batch scratch: P1 + P2 (T_LR*DI each) + db (T_LR*DBC_W)
    //                  + hS (CH*DI*DS) + csum (CH*DI) + yg_bf (T_LR*DI/2 slots)
    size_t per_b = (size_t)T_LR * DI * 2 + (size_t)T_LR * DBC_W
                 + (size_t)CH * DI * (DS + 1) + (size_t)T_LR * DI / 2;
    int Bc = 16;
    while (Bc > 1 && (size_t)Bc * per_b > scratch_avail) Bc >>= 1;

    float* e1 = mo;   // 16*128*2560 = 5.24M floats fits in mo; dead before out_proj

    // encoder
    k_enc1<<<(B_SZ * 128 * T_LR) / 256, 256, 0, stream>>>(x, enc_w1, enc_b1, e1);
    k_enc2<<<dim3(T_LR / 16, B_SZ), 256, 0, stream>>>(e1, enc_w2, enc_b2, t_buf);
    k_rmsnorm<<<BT / 4, 256, 0, stream>>>(t_buf, norm1_w, xn_buf, xn_bf, BT);

    for (int dir = 0; dir < 2; dir++) {
        const float* inW   = (const float*)d_in[7 + 9 * dir];
        const float* convW = (const float*)d_in[8 + 9 * dir];
        const float* convb = (const float*)d_in[9 + 9 * dir];
        const float* xW    = (const float*)d_in[10 + 9 * dir];
        const float* dtW   = (const float*)d_in[11 + 9 * dir];
        const float* dtb   = (const float*)d_in[12 + 9 * dir];
        const float* Alog  = (const float*)d_in[13 + 9 * dir];
        const float* Dp    = (const float*)d_in[14 + 9 * dir];
        const float* outW  = (const float*)d_in[15 + 9 * dir];
        int rev = dir;
        // cast weights for this direction
        k_cast<<<(1024 * DM) / 256, 256, 0, stream>>>(inW, inW_bf, 1024 * DM);
        k_cast<<<(DM * DI) / 256, 256, 0, stream>>>(outW, outW_bf, DM * DI);
        for (int b0 = 0; b0 < B_SZ; b0 += Bc) {
            int Tc = Bc * T_LR;
            float* P1  = scratch;
            float* P2  = scratch + (size_t)Tc * DI;
            float* db  = scratch + 2 * (size_t)Tc * DI;
            float* hS  = db + (size_t)Tc * DBC_W;
            float* csum = hS + (size_t)Bc * CH * DI * DS;
            unsigned short* yg_bf = (unsigned short*)(csum + (size_t)Bc * CH * DI);
            const float*          xnC  = xn_buf + (size_t)b0 * T_LR * DM;
            const unsigned short* xnbC = xn_bf  + (size_t)b0 * T_LR * DM;
            float*                moC  = mo     + (size_t)b0 * T_LR * DM;
            // xc_pre = xn(rev) @ inW[0:512]^T  -> P1   [MFMA bf16]
            k_gemm_bf<<<dim3(Tc / 128, DI / 128), 256, 0, stream>>>(
                xnbC, DM, inW_bf, P1, DI, nullptr, DM, rev, 0, 0);
            // depthwise causal conv + silu -> P2 (xcs)
            k_dwconv<<<((size_t)Tc * DI) / 256, 256, 0, stream>>>(P1, convW, convb, P2);
            // dbc = xcs @ xW^T -> db  [fp32, N=48]
            k_gemm<<<dim3(Tc / 64, 1), 256, 0, stream>>>(P2, DI, xW, db, DBC_W,
                                                         nullptr, DBC_W, DI, 0);
            // dt = softplus(dbc[:, :16] @ dtW^T + dtb) -> P1  [fp32, K=16]
            k_gemm<<<dim3(Tc / 64, 8), 256, 0, stream>>>(db, DBC_W, dtW, P1, DI,
                                                         dtb, DI, DTR, 2);
            // chunked selective scan (3 phases); y in place over P2
            k_scan_p1<<<(Bc * CH * DI) / 256, 256, 0, stream>>>(P1, P2, db, Alog, hS, csum);
            k_scan_p2<<<(Bc * DI * DS) / 256, 256, 0, stream>>>(hS, csum, Alog);
            k_scan_p3<<<(Bc * CH * DI) / 256, 256, 0, stream>>>(P1, P2, db, Alog, Dp, hS);
            // z = xn(rev) @ inW[512:1024]^T -> P1 (dt dead)  [MFMA bf16]
            k_gemm_bf<<<dim3(Tc / 128, DI / 128), 256, 0, stream>>>(
                xnbC, DM, inW_bf + (size_t)DI * DM, P1, DI, nullptr, DM, rev, 0, 0);
            // yg = bf16(y * silu(z))
            k_gate_bf<<<((size_t)Tc * DI) / 256, 256, 0, stream>>>(P2, P1, yg_bf);
            // mo (+)= yg @ outW^T + xn   [MFMA bf16, crev for backward]
            k_gemm_bf<<<dim3(Tc / 128, DM / 128), 256, 0, stream>>>(
                yg_bf, DI, outW_bf, moC, DM, xnC, DI, 0, rev, dir);
        }
    }

    // combined = rmsnorm(mo) -> comb (reuses xn_buf, now dead)
    float* comb = xn_buf;
    k_rmsnorm<<<BT / 4, 256, 0, stream>>>(mo, norm2_w, comb, nullptr, BT);
    // convd + bn + silu -> d_buf (reuses mo, now dead)
    float* d_buf = mo;
    k_convd<<<dim3(T_LR / 16, B_SZ), 256, 0, stream>>>(comb, t_buf, convd_w, convd_b,
                                                       bn_g, bn_b, bn_mean, bn_var, d_buf);
    // sp conv + pixel shuffle -> out
    k_sp<<<dim3(T_LR / 16, B_SZ), 128, 0, stream>>>(d_buf, sp_w, sp_b, out);
}

// Round 5
// 2802.791 us; speedup vs baseline: 3.6653x; 1.3924x over previous
//
#include <hip/hip_runtime.h>
#include <hip/hip_bf16.h>
#include <math.h>

#define B_SZ 16
#define T_LR 2560
#define BT (B_SZ * T_LR)     // 40960 tokens
#define DM 256               // d_model
#define DI 512               // d_inner
#define DS 16                // d_state
#define DTR 16               // dt_rank
#define DBC_W 48             // dt_rank + 2*d_state
#define CH 64                // scan chunks per sequence
#define CLEN (T_LR / CH)     // 40 steps per chunk

typedef __attribute__((ext_vector_type(8))) short bf16x8;
typedef __attribute__((ext_vector_type(4))) float f32x4;

__device__ __forceinline__ float silu_f(float x) {
    return x / (1.f + __expf(-x));
}
__device__ __forceinline__ unsigned short f2bf(float v) {
    __hip_bfloat16 h = __float2bfloat16(v);
    return *(unsigned short*)&h;
}
__device__ __forceinline__ int seqrev(int r) {
    int s = r / T_LR, t = r % T_LR;
    return s * T_LR + (T_LR - 1 - t);
}

// ---------------------------------------------------------------------------
// enc conv1: x(16,64,2560) -> e1(16,128,2560), k=3 same pad, silu  [fp32]
// ---------------------------------------------------------------------------
__global__ __launch_bounds__(256) void k_enc1(const float* __restrict__ x,
                                              const float* __restrict__ w,
                                              const float* __restrict__ bias,
                                              float* __restrict__ out) {
    int idx = blockIdx.x * 256 + threadIdx.x;       // b*128*2560
    int t = idx % T_LR;
    int c = (idx / T_LR) & 127;
    int b = idx / (T_LR * 128);
    float acc = bias[c];
    const float* wp = w + c * 64 * 3;
    const float* xp = x + (size_t)b * 64 * T_LR + t;
    #pragma unroll 4
    for (int ci = 0; ci < 64; ci++) {
        float w0 = wp[ci * 3 + 0], w1 = wp[ci * 3 + 1], w2 = wp[ci * 3 + 2];
        const float* xr = xp + (size_t)ci * T_LR;
        if (t > 0) acc += xr[-1] * w0;
        acc += xr[0] * w1;
        if (t < T_LR - 1) acc += xr[1] * w2;
    }
    out[idx] = silu_f(acc);
}

// ---------------------------------------------------------------------------
// transpose e1 (b,128,T) f32 -> e1t (b,T,128) bf16
// ---------------------------------------------------------------------------
__global__ __launch_bounds__(256) void k_transp(const float* __restrict__ e1,
                                                unsigned short* __restrict__ e1t) {
    __shared__ float s[32][33];
    int b = blockIdx.z;
    int t0 = blockIdx.x * 32, c0 = blockIdx.y * 32;
    int tx = threadIdx.x & 31, ty = threadIdx.x >> 5;   // 32 x 8
    #pragma unroll
    for (int j = 0; j < 4; j++) {
        int c = c0 + ty + j * 8;
        s[ty + j * 8][tx] = e1[((size_t)b * 128 + c) * T_LR + t0 + tx];
    }
    __syncthreads();
    #pragma unroll
    for (int j = 0; j < 4; j++) {
        int t = t0 + ty + j * 8;
        e1t[((size_t)b * T_LR + t) * 128 + c0 + tx] = f2bf(s[tx][ty + j * 8]);
    }
}

// ---------------------------------------------------------------------------
// weight rearrange: in (N,K,3) f32 -> out [3][N][K] bf16
// ---------------------------------------------------------------------------
__global__ __launch_bounds__(256) void k_wrearr(const float* __restrict__ in,
                                                unsigned short* __restrict__ out,
                                                int N, int K) {
    int i = blockIdx.x * 256 + threadIdx.x;     // n*K + ci
    if (i >= N * K) return;
    int n = i / K, ci = i % K;
    #pragma unroll
    for (int k = 0; k < 3; k++)
        out[((size_t)k * N + n) * K + ci] = f2bf(in[((size_t)n * K + ci) * 3 + k]);
}

// ---------------------------------------------------------------------------
// fold BN into alpha/beta (256 ch): v = alpha*conv + beta
// ---------------------------------------------------------------------------
__global__ __launch_bounds__(256) void k_bnfold(const float* __restrict__ cb,
                                                const float* __restrict__ bng,
                                                const float* __restrict__ bnb,
                                                const float* __restrict__ bnm,
                                                const float* __restrict__ bnv,
                                                float* __restrict__ alpha,
                                                float* __restrict__ beta) {
    int c = threadIdx.x;
    float a = bng[c] * rsqrtf(bnv[c] + 1e-5f);
    alpha[c] = a;
    beta[c] = (cb[c] - bnm[c]) * a + bnb[c];
}

// ---------------------------------------------------------------------------
// implicit-GEMM k=3 "same" conv via MFMA.
// out[t,n] = act(alpha[n] * (sum_tap sum_ci In[t+tap-1,ci] W[tap][n][ci]) + beta[n])
// In = A1 (bf16 (BT,K1)) [channel-concat A2 (BT,K2) if non-null]
// W bf16 [3][N][K1+K2].  Tile 128x128, 4 waves, halo-staged A (130 rows).
// store: pixsh ? pixel-shuffle fp32 : (outf fp32 and/or outb bf16, ld=N)
// ---------------------------------------------------------------------------
__global__ __launch_bounds__(256) void k_conv3_bf(const unsigned short* __restrict__ A1, int K1,
                                                  const unsigned short* __restrict__ A2, int K2,
                                                  const unsigned short* __restrict__ W,
                                                  const float* __restrict__ alpha,
                                                  const float* __restrict__ beta,
                                                  float* __restrict__ outf,
                                                  unsigned short* __restrict__ outb,
                                                  int N, int dosilu, int pixsh) {
    int Kt = K1 + K2;
    __shared__ unsigned short As[130][40];
    __shared__ unsigned short Bs[3][128][40];
    int tid = threadIdx.x;
    int wave = tid >> 6, lane = tid & 63;
    int wm = (wave >> 1) * 64, wn = (wave & 1) * 64;
    int m0 = blockIdx.x * 128, n0 = blockIdx.y * 128;
    int b = m0 / T_LR, t0 = m0 % T_LR;
    int q = lane >> 4, ml = lane & 15;
    f32x4 acc[4][4] = {};
    for (int k0 = 0; k0 < Kt; k0 += 32) {
        __syncthreads();
        // stage A halo tile: LDS row r <-> token t0-1+r
        for (int i = tid; i < 520; i += 256) {
            int row = i >> 2, cq = i & 3;
            int t = t0 - 1 + row;
            uint4 v = make_uint4(0u, 0u, 0u, 0u);
            if (t >= 0 && t < T_LR) {
                int col = k0 + cq * 8;
                const unsigned short* src = (col < K1)
                    ? A1 + (size_t)(b * T_LR + t) * K1 + col
                    : A2 + (size_t)(b * T_LR + t) * K2 + (col - K1);
                v = *(const uint4*)src;
            }
            *(uint4*)&As[row][cq * 8] = v;
        }
        // stage B: 3 taps x 128 rows x 32 cols
        for (int i = tid; i < 1536; i += 256) {
            int tap = i >> 9;
            int r = (i >> 2) & 127;
            int cq = i & 3;
            *(uint4*)&Bs[tap][r][cq * 8] =
                *(const uint4*)(W + ((size_t)tap * N + n0 + r) * Kt + k0 + cq * 8);
        }
        __syncthreads();
        #pragma unroll
        for (int tap = 0; tap < 3; tap++) {
            bf16x8 bfr[4];
            #pragma unroll
            for (int ni = 0; ni < 4; ni++)
                bfr[ni] = *(const bf16x8*)&Bs[tap][wn + ni * 16 + ml][q * 8];
            #pragma unroll
            for (int mi = 0; mi < 4; mi++) {
                bf16x8 af = *(const bf16x8*)&As[wm + mi * 16 + ml + tap][q * 8];
                #pragma unroll
                for (int ni = 0; ni < 4; ni++)
                    acc[mi][ni] = __builtin_amdgcn_mfma_f32_16x16x32_bf16(af, bfr[ni], acc[mi][ni], 0, 0, 0);
            }
        }
    }
    #pragma unroll
    for (int mi = 0; mi < 4; mi++) {
        #pragma unroll
        for (int r = 0; r < 4; r++) {
            int mr = m0 + wm + mi * 16 + q * 4 + r;
            int t = mr - b * T_LR;
            #pragma unroll
            for (int ni = 0; ni < 4; ni++) {
                int col = n0 + wn + ni * 16 + ml;
                float a = alpha ? alpha[col] : 1.f;
                float v = acc[mi][ni][r] * a + beta[col];
                if (dosilu) v = silu_f(v);
                if (pixsh) {
                    int c2 = col >> 1, rr = col & 1;
                    outf[(((size_t)b * 64 + c2) * T_LR + t) * 2 + rr] = v;
                } else {
                    size_t o = (size_t)mr * N + col;
                    if (outf) outf[o] = v;
                    if (outb) outb[o] = f2bf(v);
                }
            }
        }
    }
}

// ---------------------------------------------------------------------------
// rmsnorm over last dim (256). One wave per token. fp32 and/or bf16 out.
// ---------------------------------------------------------------------------
__global__ __launch_bounds__(256) void k_rmsnorm(const float* __restrict__ in1,
                                                 const float* __restrict__ w,
                                                 float* __restrict__ out,
                                                 unsigned short* __restrict__ out_bf,
                                                 int ntok) {
    int tok = (blockIdx.x * 256 + threadIdx.x) >> 6;
    int lane = threadIdx.x & 63;
    if (tok >= ntok) return;
    float4 v = ((const float4*)(in1 + (size_t)tok * DM))[lane];
    float ss = v.x * v.x + v.y * v.y + v.z * v.z + v.w * v.w;
    #pragma unroll
    for (int off = 32; off > 0; off >>= 1) ss += __shfl_xor(ss, off);
    float sc = rsqrtf(ss * (1.f / 256.f) + 1e-6f);
    float4 wv = ((const float4*)w)[lane];
    float4 o;
    o.x = v.x * sc * wv.x; o.y = v.y * sc * wv.y;
    o.z = v.z * sc * wv.z; o.w = v.w * sc * wv.w;
    if (out) ((float4*)(out + (size_t)tok * DM))[lane] = o;
    if (out_bf) {
        ushort4 ob;
        ob.x = f2bf(o.x); ob.y = f2bf(o.y); ob.z = f2bf(o.z); ob.w = f2bf(o.w);
        ((ushort4*)(out_bf + (size_t)tok * DM))[lane] = ob;
    }
}

// ---------------------------------------------------------------------------
// f32 -> bf16 cast (weights)
// ---------------------------------------------------------------------------
__global__ __launch_bounds__(256) void k_cast(const float* __restrict__ in,
                                              unsigned short* __restrict__ out, int n) {
    int i = blockIdx.x * 256 + threadIdx.x;
    if (i < n) out[i] = f2bf(in[i]);
}

// ---------------------------------------------------------------------------
// gate + cast: yg = bf16(y * silu(z))
// ---------------------------------------------------------------------------
__global__ __launch_bounds__(256) void k_gate_bf(const float* __restrict__ y,
                                                 const float* __restrict__ z,
                                                 unsigned short* __restrict__ yg) {
    int i = blockIdx.x * 256 + threadIdx.x;
    yg[i] = f2bf(y[i] * silu_f(z[i]));
}

// ---------------------------------------------------------------------------
// bf16 MFMA GEMM: C[M,N](f32) = A[M,K](bf16) @ Bw[N,K](bf16)^T (+res)(+C accum)
// 128x128 tile, 4 waves, each 64x64 via 4x4 mfma 16x16x32.
// ---------------------------------------------------------------------------
__global__ __launch_bounds__(256) void k_gemm_bf(const unsigned short* __restrict__ A, int lda,
                                                 const unsigned short* __restrict__ Bw,
                                                 float* C, int ldc,
                                                 const float* __restrict__ res,
                                                 int K, int arev, int crev, int accum) {
    __shared__ unsigned short As[128][40];
    __shared__ unsigned short Bs[128][40];
    int tid = threadIdx.x;
    int wave = tid >> 6, lane = tid & 63;
    int wm = (wave >> 1) * 64, wn = (wave & 1) * 64;
    int m0 = blockIdx.x * 128, n0 = blockIdx.y * 128;
    int sc = tid & 3;
    int sr = tid >> 2;
    int ar0 = m0 + sr, ar1 = m0 + sr + 64;
    if (arev) { ar0 = seqrev(ar0); ar1 = seqrev(ar1); }
    const unsigned short* ap0 = A + (size_t)ar0 * lda + sc * 8;
    const unsigned short* ap1 = A + (size_t)ar1 * lda + sc * 8;
    const unsigned short* bp0 = Bw + (size_t)(n0 + sr) * K + sc * 8;
    const unsigned short* bp1 = Bw + (size_t)(n0 + sr + 64) * K + sc * 8;
    f32x4 acc[4][4] = {};
    int q = lane >> 4, ml = lane & 15;
    for (int k0 = 0; k0 < K; k0 += 32) {
        uint4 a0 = *(const uint4*)(ap0 + k0);
        uint4 a1 = *(const uint4*)(ap1 + k0);
        uint4 b0 = *(const uint4*)(bp0 + k0);
        uint4 b1 = *(const uint4*)(bp1 + k0);
        __syncthreads();
        *(uint4*)&As[sr][sc * 8]      = a0;
        *(uint4*)&As[sr + 64][sc * 8] = a1;
        *(uint4*)&Bs[sr][sc * 8]      = b0;
        *(uint4*)&Bs[sr + 64][sc * 8] = b1;
        __syncthreads();
        bf16x8 af[4], bfr[4];
        #pragma unroll
        for (int mi = 0; mi < 4; mi++)
            af[mi] = *(const bf16x8*)&As[wm + mi * 16 + ml][q * 8];
        #pragma unroll
        for (int ni = 0; ni < 4; ni++)
            bfr[ni] = *(const bf16x8*)&Bs[wn + ni * 16 + ml][q * 8];
        #pragma unroll
        for (int mi = 0; mi < 4; mi++)
            #pragma unroll
            for (int ni = 0; ni < 4; ni++)
                acc[mi][ni] = __builtin_amdgcn_mfma_f32_16x16x32_bf16(af[mi], bfr[ni], acc[mi][ni], 0, 0, 0);
    }
    #pragma unroll
    for (int mi = 0; mi < 4; mi++) {
        #pragma unroll
        for (int r = 0; r < 4; r++) {
            int mr = m0 + wm + mi * 16 + q * 4 + r;
            int orow = crev ? seqrev(mr) : mr;
            float* crow = C + (size_t)orow * ldc;
            const float* rrow = res ? res + (size_t)orow * ldc : nullptr;
            #pragma unroll
            for (int ni = 0; ni < 4; ni++) {
                int col = n0 + wn + ni * 16 + ml;
                float v = acc[mi][ni][r];
                if (res) v += rrow[col];
                if (accum) v += crow[col];
                crow[col] = v;
            }
        }
    }
}

// ---------------------------------------------------------------------------
// generic tiled fp32 GEMM (x_proj N=48 and dt K=16)
// ---------------------------------------------------------------------------
__global__ __launch_bounds__(256) void k_gemm(const float* __restrict__ A, int lda,
                                              const float* __restrict__ Bw,
                                              float* C, int ldc,
                                              const float* __restrict__ bias,
                                              int N, int K, int act) {
    __shared__ float As[16][68];
    __shared__ float Bs[16][68];
    int bm = blockIdx.x, bn = blockIdx.y;
    int tid = threadIdx.x;
    int tx = tid & 15, ty = tid >> 4;
    int lm = tid & 63, kq = tid >> 6;
    float acc[4][4] = {};
    int arow = bm * 64 + lm;
    int brow = bn * 64 + lm;
    const float4* ap = (const float4*)(A + (size_t)arow * lda) + kq;
    bool bvalid = brow < N;
    const float4* bp = (const float4*)(Bw + (size_t)brow * K) + kq;
    for (int k0 = 0; k0 < K; k0 += 16) {
        float4 av = ap[0]; ap += 4;
        float4 bv = make_float4(0.f, 0.f, 0.f, 0.f);
        if (bvalid) { bv = bp[0]; bp += 4; }
        As[kq * 4 + 0][lm] = av.x; As[kq * 4 + 1][lm] = av.y;
        As[kq * 4 + 2][lm] = av.z; As[kq * 4 + 3][lm] = av.w;
        Bs[kq * 4 + 0][lm] = bv.x; Bs[kq * 4 + 1][lm] = bv.y;
        Bs[kq * 4 + 2][lm] = bv.z; Bs[kq * 4 + 3][lm] = bv.w;
        __syncthreads();
        #pragma unroll
        for (int kk = 0; kk < 16; kk++) {
            float4 a = *(const float4*)&As[kk][ty * 4];
            float4 b = *(const float4*)&Bs[kk][tx * 4];
            acc[0][0] += a.x * b.x; acc[0][1] += a.x * b.y; acc[0][2] += a.x * b.z; acc[0][3] += a.x * b.w;
            acc[1][0] += a.y * b.x; acc[1][1] += a.y * b.y; acc[1][2] += a.y * b.z; acc[1][3] += a.y * b.w;
            acc[2][0] += a.z * b.x; acc[2][1] += a.z * b.y; acc[2][2] += a.z * b.z; acc[2][3] += a.z * b.w;
            acc[3][0] += a.w * b.x; acc[3][1] += a.w * b.y; acc[3][2] += a.w * b.z; acc[3][3] += a.w * b.w;
        }
        __syncthreads();
    }
    #pragma unroll
    for (int i = 0; i < 4; i++) {
        int mr = bm * 64 + ty * 4 + i;
        #pragma unroll
        for (int j = 0; j < 4; j++) {
            int n = bn * 64 + tx * 4 + j;
            if (n < N) {
                float v = acc[i][j];
                if (bias) v += bias[n];
                if (act == 2) v = (v > 20.f) ? v : log1pf(__expf(v));
                C[(size_t)mr * ldc + n] = v;
            }
        }
    }
}

// ---------------------------------------------------------------------------
// depthwise causal conv k=4 + bias + silu.  xc (Tc,512) -> out (Tc,512)
// ---------------------------------------------------------------------------
__global__ __launch_bounds__(256) void k_dwconv(const float* __restrict__ xc,
                                                const float* __restrict__ cw,
                                                const float* __restrict__ cb,
                                                float* __restrict__ out) {
    int idx = blockIdx.x * 256 + threadIdx.x;   // Tc*512
    int d = idx & (DI - 1);
    int row = idx >> 9;
    int t = row % T_LR;
    float acc = cb[d];
    #pragma unroll
    for (int k = 0; k < 4; k++) {
        int tt = t - 3 + k;
        if (tt >= 0) acc += xc[(size_t)(row - t + tt) * DI + d] * cw[d * 4 + k];
    }
    out[idx] = silu_f(acc);
}

// ---------------------------------------------------------------------------
// scan phase 1: per (bl, chunk, d) thread. Chunk-local scan from h=0.
// ---------------------------------------------------------------------------
__global__ __launch_bounds__(256) void k_scan_p1(const float* __restrict__ dt,
                                                 const float* __restrict__ x,
                                                 const float* __restrict__ dbc,
                                                 const float* __restrict__ Alog,
                                                 float* __restrict__ hS,
                                                 float* __restrict__ csum) {
    int gid = blockIdx.x * 256 + threadIdx.x;   // (bl*CH + c)*DI + d
    int d = gid & (DI - 1);
    int bcix = gid >> 9;
    int c = bcix & (CH - 1);
    int bl = bcix >> 6;
    float A[DS], h[DS];
    #pragma unroll
    for (int n = 0; n < DS; n++) { A[n] = -__expf(Alog[d * DS + n]); h[n] = 0.f; }
    int tbase = c * CLEN;
    const float* dtp = dt + ((size_t)bl * T_LR + tbase) * DI + d;
    const float* xp  = x  + ((size_t)bl * T_LR + tbase) * DI + d;
    const float* bcp = dbc + ((size_t)bl * T_LR + tbase) * DBC_W;
    float S = 0.f;
    for (int t = 0; t < CLEN; t++) {
        float dtv = dtp[(size_t)t * DI];
        float xv  = xp[(size_t)t * DI];
        float dtx = dtv * xv;
        const float* bc = bcp + (size_t)t * DBC_W;
        S += dtv;
        #pragma unroll
        for (int n = 0; n < DS; n++)
            h[n] = __expf(dtv * A[n]) * h[n] + dtx * bc[16 + n];
    }
    float* hp = hS + (size_t)gid * DS;
    #pragma unroll
    for (int n = 0; n < DS; n++) hp[n] = h[n];
    csum[gid] = S;
}

// ---------------------------------------------------------------------------
// scan phase 2: per (bl, d, n) thread; sequential over CH chunks, in place.
// ---------------------------------------------------------------------------
__global__ __launch_bounds__(256) void k_scan_p2(float* __restrict__ hS,
                                                 const float* __restrict__ csum,
                                                 const float* __restrict__ Alog) {
    int gid = blockIdx.x * 256 + threadIdx.x;   // (bl*DI + d)*DS + n
    int n = gid & (DS - 1);
    int d = (gid >> 4) & (DI - 1);
    int bl = gid >> 13;
    float An = -__expf(Alog[d * DS + n]);
    float hs = 0.f;
    for (int c = 0; c < CH; c++) {
        size_t base = ((size_t)(bl * CH + c) * DI + d);
        float he = hS[base * DS + n];
        float S  = csum[base];
        hS[base * DS + n] = hs;
        hs = __expf(An * S) * hs + he;
    }
}

// ---------------------------------------------------------------------------
// scan phase 3: corrected chunk-start state, emits y in place over x.
// ---------------------------------------------------------------------------
__global__ __launch_bounds__(256) void k_scan_p3(const float* __restrict__ dt,
                                                 float* x,
                                                 const float* __restrict__ dbc,
                                                 const float* __restrict__ Alog,
                                                 const float* __restrict__ Dp,
                                                 const float* __restrict__ hS) {
    int gid = blockIdx.x * 256 + threadIdx.x;   // (bl*CH + c)*DI + d
    int d = gid & (DI - 1);
    int bcix = gid >> 9;
    int c = bcix & (CH - 1);
    int bl = bcix >> 6;
    float A[DS], h[DS];
    const float* hp = hS + (size_t)gid * DS;
    #pragma unroll
    for (int n = 0; n < DS; n++) { A[n] = -__expf(Alog[d * DS + n]); h[n] = hp[n]; }
    float Dd = Dp[d];
    int tbase = c * CLEN;
    const float* dtp = dt + ((size_t)bl * T_LR + tbase) * DI + d;
    float* xp  = x  + ((size_t)bl * T_LR + tbase) * DI + d;
    const float* bcp = dbc + ((size_t)bl * T_LR + tbase) * DBC_W;
    for (int t = 0; t < CLEN; t++) {
        float dtv = dtp[(size_t)t * DI];
        float xv  = xp[(size_t)t * DI];
        float dtx = dtv * xv;
        const float* bc = bcp + (size_t)t * DBC_W;
        float acc = 0.f;
        #pragma unroll
        for (int n = 0; n < DS; n++) {
            h[n] = __expf(dtv * A[n]) * h[n] + dtx * bc[16 + n];
            acc += h[n] * bc[32 + n];
        }
        xp[(size_t)t * DI] = acc + xv * Dd;
    }
}

// ---------------------------------------------------------------------------
extern "C" void kernel_launch(void* const* d_in, const int* in_sizes, int n_in,
                              void* d_out, int out_size, void* d_ws, size_t ws_size,
                              hipStream_t stream) {
    const float* x       = (const float*)d_in[0];
    const float* enc_w1  = (const float*)d_in[1];
    const float* enc_b1  = (const float*)d_in[2];
    const float* enc_w2  = (const float*)d_in[3];
    const float* enc_b2  = (const float*)d_in[4];
    const float* norm1_w = (const float*)d_in[5];
    const float* norm2_w = (const float*)d_in[6];
    const float* convd_w = (const float*)d_in[25];
    const float* convd_b = (const float*)d_in[26];
    const float* bn_g    = (const float*)d_in[27];
    const float* bn_b    = (const float*)d_in[28];
    const float* bn_mean = (const float*)d_in[29];
    const float* bn_var  = (const float*)d_in[30];
    const float* sp_w    = (const float*)d_in[31];
    const float* sp_b    = (const float*)d_in[32];
    float* out = (float*)d_out;

    // ---- workspace layout (float slots) ----
    float* ws = (float*)d_ws;
    size_t availf = ws_size / sizeof(float);
    size_t o = 0;
    float* t_buf  = ws + o; o += (size_t)BT * DM;
    float* xn_buf = ws + o; o += (size_t)BT * DM;       // later: comb_bf overlay
    float* mo     = ws + o; o += (size_t)BT * DM;       // early: e1; late: d_bf overlay
    unsigned short* xn_bf = (unsigned short*)(ws + o); o += (size_t)BT * DM / 2;
    unsigned short* tb_bf = (unsigned short*)(ws + o); o += (size_t)BT * DM / 2;
    unsigned short* inW_bf  = (unsigned short*)(ws + o); o += (1024 * DM) / 2;
    unsigned short* outW_bf = (unsigned short*)(ws + o); o += (DM * DI) / 2;
    unsigned short* W2r  = (unsigned short*)(ws + o); o += (3 * 256 * 128) / 2;
    unsigned short* Wdr  = (unsigned short*)(ws + o); o += (3 * 256 * 512) / 2;
    unsigned short* Wspr = (unsigned short*)(ws + o); o += (3 * 128 * 256) / 2;
    float* alpha_d = ws + o; o += 256;
    float* beta_d  = ws + o; o += 256;
    size_t persist = o;
    float* scratch = ws + persist;
    size_t scratch_avail = (availf > persist) ? (availf - persist) : 0;
    size_t per_b = (size_t)T_LR * DI * 2 + (size_t)T_LR * DBC_W
                 + (size_t)CH * DI * (DS + 1) + (size_t)T_LR * DI / 2;
    int Bc = 16;
    while (Bc > 1 && (size_t)Bc * per_b > scratch_avail) Bc >>= 1;

    float* e1 = mo;                                      // (b,128,T) f32, dies pre-mamba
    unsigned short* e1t = (unsigned short*)scratch;      // (b,T,128) bf16
    unsigned short* comb_bf = (unsigned short*)xn_buf;   // overlay after xn dead
    unsigned short* d_bf = (unsigned short*)mo;          // overlay after mo dead

    // weight prep
    k_wrearr<<<(256 * 128 + 255) / 256, 256, 0, stream>>>(enc_w2, W2r, 256, 128);
    k_wrearr<<<(256 * 512 + 255) / 256, 256, 0, stream>>>(convd_w, Wdr, 256, 512);
    k_wrearr<<<(128 * 256 + 255) / 256, 256, 0, stream>>>(sp_w, Wspr, 128, 256);
    k_bnfold<<<1, 256, 0, stream>>>(convd_b, bn_g, bn_b, bn_mean, bn_var, alpha_d, beta_d);

    // encoder
    k_enc1<<<(B_SZ * 128 * T_LR) / 256, 256, 0, stream>>>(x, enc_w1, enc_b1, e1);
    k_transp<<<dim3(T_LR / 32, 4, B_SZ), 256, 0, stream>>>(e1, e1t);
    k_conv3_bf<<<dim3(BT / 128, 2), 256, 0, stream>>>(e1t, 128, nullptr, 0, W2r,
                                                      nullptr, enc_b2, t_buf, tb_bf, 256, 1, 0);
    k_rmsnorm<<<BT / 4, 256, 0, stream>>>(t_buf, norm1_w, xn_buf, xn_bf, BT);

    for (int dir = 0; dir < 2; dir++) {
        const float* inW   = (const float*)d_in[7 + 9 * dir];
        const float* convW = (const float*)d_in[8 + 9 * dir];
        const float* convb = (const float*)d_in[9 + 9 * dir];
        const float* xW    = (const float*)d_in[10 + 9 * dir];
        const float* dtW   = (const float*)d_in[11 + 9 * dir];
        const float* dtb   = (const float*)d_in[12 + 9 * dir];
        const float* Alog  = (const float*)d_in[13 + 9 * dir];
        const float* Dp    = (const float*)d_in[14 + 9 * dir];
        const float* outW  = (const float*)d_in[15 + 9 * dir];
        int rev = dir;
        k_cast<<<(1024 * DM) / 256, 256, 0, stream>>>(inW, inW_bf, 1024 * DM);
        k_cast<<<(DM * DI) / 256, 256, 0, stream>>>(outW, outW_bf, DM * DI);
        for (int b0 = 0; b0 < B_SZ; b0 += Bc) {
            int Tc = Bc * T_LR;
            float* P1  = scratch;
            float* P2  = scratch + (size_t)Tc * DI;
            float* db  = scratch + 2 * (size_t)Tc * DI;
            float* hS  = db + (size_t)Tc * DBC_W;
            float* csum = hS + (size_t)Bc * CH * DI * DS;
            unsigned short* yg_bf = (unsigned short*)(csum + (size_t)Bc * CH * DI);
            const float*          xnC  = xn_buf + (size_t)b0 * T_LR * DM;
            const unsigned short* xnbC = xn_bf  + (size_t)b0 * T_LR * DM;
            float*                moC  = mo     + (size_t)b0 * T_LR * DM;
            // xc_pre = xn(rev) @ inW[0:512]^T -> P1   [MFMA]
            k_gemm_bf<<<dim3(Tc / 128, DI / 128), 256, 0, stream>>>(
                xnbC, DM, inW_bf, P1, DI, nullptr, DM, rev, 0, 0);
            // depthwise conv + silu -> P2
            k_dwconv<<<((size_t)Tc * DI) / 256, 256, 0, stream>>>(P1, convW, convb, P2);
            // dbc = xcs @ xW^T -> db  [fp32, N=48]
            k_gemm<<<dim3(Tc / 64, 1), 256, 0, stream>>>(P2, DI, xW, db, DBC_W,
                                                         nullptr, DBC_W, DI, 0);
            // dt = softplus(dbc[:,:16] @ dtW^T + dtb) -> P1  [fp32, K=16]
            k_gemm<<<dim3(Tc / 64, 8), 256, 0, stream>>>(db, DBC_W, dtW, P1, DI,
                                                         dtb, DI, DTR, 2);
            // chunked scan; y in place over P2
            k_scan_p1<<<(Bc * CH * DI) / 256, 256, 0, stream>>>(P1, P2, db, Alog, hS, csum);
            k_scan_p2<<<(Bc * DI * DS) / 256, 256, 0, stream>>>(hS, csum, Alog);
            k_scan_p3<<<(Bc * CH * DI) / 256, 256, 0, stream>>>(P1, P2, db, Alog, Dp, hS);
            // z = xn(rev) @ inW[512:1024]^T -> P1   [MFMA]
            k_gemm_bf<<<dim3(Tc / 128, DI / 128), 256, 0, stream>>>(
                xnbC, DM, inW_bf + (size_t)DI * DM, P1, DI, nullptr, DM, rev, 0, 0);
            // yg = bf16(y * silu(z))
            k_gate_bf<<<((size_t)Tc * DI) / 256, 256, 0, stream>>>(P2, P1, yg_bf);
            // mo (+)= yg @ outW^T + xn   [MFMA]
            k_gemm_bf<<<dim3(Tc / 128, DM / 128), 256, 0, stream>>>(
                yg_bf, DI, outW_bf, moC, DM, xnC, DI, 0, rev, dir);
        }
    }

    // combined = rmsnorm(mo) -> comb_bf (xn_buf overlay; xn dead)
    k_rmsnorm<<<BT / 4, 256, 0, stream>>>(mo, norm2_w, nullptr, comb_bf, BT);
    // convd + bn + silu -> d_bf (mo overlay; mo dead)   [MFMA implicit conv]
    k_conv3_bf<<<dim3(BT / 128, 2), 256, 0, stream>>>(comb_bf, 256, tb_bf, 256, Wdr,
                                                      alpha_d, beta_d, nullptr, d_bf, 256, 1, 0);
    // sp conv + pixel shuffle -> out   [MFMA implicit conv]
    k_conv3_bf<<<dim3(BT / 128, 1), 256, 0, stream>>>(d_bf, 256, nullptr, 0, Wspr,
                                                      nullptr, sp_b, out, nullptr, 128, 0, 1);
}

// Round 6
// 2312.606 us; speedup vs baseline: 4.4423x; 1.2120x over previous
//
#include <hip/hip_runtime.h>
#include <hip/hip_bf16.h>
#include <math.h>

#define B_SZ 16
#define T_LR 2560
#define BT (B_SZ * T_LR)     // 40960 tokens
#define DM 256               // d_model
#define DI 512               // d_inner
#define DS 16                // d_state
#define DTR 16               // dt_rank
#define DBC_W 48             // dt_rank + 2*d_state
#define CH 64                // scan chunks per sequence
#define CLEN (T_LR / CH)     // 40 steps per chunk

typedef __attribute__((ext_vector_type(8))) short bf16x8;
typedef __attribute__((ext_vector_type(4))) float f32x4;

__device__ __forceinline__ float silu_f(float x) {
    return x / (1.f + __expf(-x));
}
__device__ __forceinline__ unsigned short f2bf(float v) {
    __hip_bfloat16 h = __float2bfloat16(v);
    return *(unsigned short*)&h;
}
__device__ __forceinline__ int seqrev(int r) {
    int s = r / T_LR, t = r % T_LR;
    return s * T_LR + (T_LR - 1 - t);
}

// ---------------------------------------------------------------------------
// transpose (b,nch,T) f32 -> (b,T,nch) bf16
// ---------------------------------------------------------------------------
__global__ __launch_bounds__(256) void k_transp(const float* __restrict__ in,
                                                unsigned short* __restrict__ outb,
                                                int nch) {
    __shared__ float s[32][33];
    int b = blockIdx.z;
    int t0 = blockIdx.x * 32, c0 = blockIdx.y * 32;
    int tx = threadIdx.x & 31, ty = threadIdx.x >> 5;   // 32 x 8
    #pragma unroll
    for (int j = 0; j < 4; j++) {
        int c = c0 + ty + j * 8;
        s[ty + j * 8][tx] = in[((size_t)b * nch + c) * T_LR + t0 + tx];
    }
    __syncthreads();
    #pragma unroll
    for (int j = 0; j < 4; j++) {
        int t = t0 + ty + j * 8;
        outb[((size_t)b * T_LR + t) * nch + c0 + tx] = f2bf(s[tx][ty + j * 8]);
    }
}

// ---------------------------------------------------------------------------
// weight rearrange: in (N,K,3) f32 -> out [3][N][K] bf16
// ---------------------------------------------------------------------------
__global__ __launch_bounds__(256) void k_wrearr(const float* __restrict__ in,
                                                unsigned short* __restrict__ out,
                                                int N, int K) {
    int i = blockIdx.x * 256 + threadIdx.x;     // n*K + ci
    if (i >= N * K) return;
    int n = i / K, ci = i % K;
    #pragma unroll
    for (int k = 0; k < 3; k++)
        out[((size_t)k * N + n) * K + ci] = f2bf(in[((size_t)n * K + ci) * 3 + k]);
}

// ---------------------------------------------------------------------------
// fold BN into alpha/beta (256 ch): v = alpha*conv + beta
// ---------------------------------------------------------------------------
__global__ __launch_bounds__(256) void k_bnfold(const float* __restrict__ cb,
                                                const float* __restrict__ bng,
                                                const float* __restrict__ bnb,
                                                const float* __restrict__ bnm,
                                                const float* __restrict__ bnv,
                                                float* __restrict__ alpha,
                                                float* __restrict__ beta) {
    int c = threadIdx.x;
    float a = bng[c] * rsqrtf(bnv[c] + 1e-5f);
    alpha[c] = a;
    beta[c] = (cb[c] - bnm[c]) * a + bnb[c];
}

// ---------------------------------------------------------------------------
// implicit-GEMM k=3 "same" conv via MFMA.
// out[t,n] = act(alpha[n] * (sum_tap sum_ci In[t+tap-1,ci] W[tap][n][ci]) + beta[n])
// In = A1 (bf16 (BT,K1)) [channel-concat A2 (BT,K2) if non-null]
// W bf16 [3][N][K1+K2].  Tile 128x128, 4 waves, halo-staged A (130 rows).
// store: pixsh ? pixel-shuffle fp32 : (outf fp32 and/or outb bf16, ld=N)
// ---------------------------------------------------------------------------
__global__ __launch_bounds__(256) void k_conv3_bf(const unsigned short* __restrict__ A1, int K1,
                                                  const unsigned short* __restrict__ A2, int K2,
                                                  const unsigned short* __restrict__ W,
                                                  const float* __restrict__ alpha,
                                                  const float* __restrict__ beta,
                                                  float* __restrict__ outf,
                                                  unsigned short* __restrict__ outb,
                                                  int N, int dosilu, int pixsh) {
    int Kt = K1 + K2;
    __shared__ unsigned short As[130][40];
    __shared__ unsigned short Bs[3][128][40];
    int tid = threadIdx.x;
    int wave = tid >> 6, lane = tid & 63;
    int wm = (wave >> 1) * 64, wn = (wave & 1) * 64;
    int m0 = blockIdx.x * 128, n0 = blockIdx.y * 128;
    int b = m0 / T_LR, t0 = m0 % T_LR;
    int q = lane >> 4, ml = lane & 15;
    f32x4 acc[4][4] = {};
    for (int k0 = 0; k0 < Kt; k0 += 32) {
        __syncthreads();
        // stage A halo tile: LDS row r <-> token t0-1+r
        for (int i = tid; i < 520; i += 256) {
            int row = i >> 2, cq = i & 3;
            int t = t0 - 1 + row;
            uint4 v = make_uint4(0u, 0u, 0u, 0u);
            if (t >= 0 && t < T_LR) {
                int col = k0 + cq * 8;
                const unsigned short* src = (col < K1)
                    ? A1 + (size_t)(b * T_LR + t) * K1 + col
                    : A2 + (size_t)(b * T_LR + t) * K2 + (col - K1);
                v = *(const uint4*)src;
            }
            *(uint4*)&As[row][cq * 8] = v;
        }
        // stage B: 3 taps x 128 rows x 32 cols
        for (int i = tid; i < 1536; i += 256) {
            int tap = i >> 9;
            int r = (i >> 2) & 127;
            int cq = i & 3;
            *(uint4*)&Bs[tap][r][cq * 8] =
                *(const uint4*)(W + ((size_t)tap * N + n0 + r) * Kt + k0 + cq * 8);
        }
        __syncthreads();
        #pragma unroll
        for (int tap = 0; tap < 3; tap++) {
            bf16x8 bfr[4];
            #pragma unroll
            for (int ni = 0; ni < 4; ni++)
                bfr[ni] = *(const bf16x8*)&Bs[tap][wn + ni * 16 + ml][q * 8];
            #pragma unroll
            for (int mi = 0; mi < 4; mi++) {
                bf16x8 af = *(const bf16x8*)&As[wm + mi * 16 + ml + tap][q * 8];
                #pragma unroll
                for (int ni = 0; ni < 4; ni++)
                    acc[mi][ni] = __builtin_amdgcn_mfma_f32_16x16x32_bf16(af, bfr[ni], acc[mi][ni], 0, 0, 0);
            }
        }
    }
    #pragma unroll
    for (int mi = 0; mi < 4; mi++) {
        #pragma unroll
        for (int r = 0; r < 4; r++) {
            int mr = m0 + wm + mi * 16 + q * 4 + r;
            int t = mr - b * T_LR;
            #pragma unroll
            for (int ni = 0; ni < 4; ni++) {
                int col = n0 + wn + ni * 16 + ml;
                float a = alpha ? alpha[col] : 1.f;
                float v = acc[mi][ni][r] * a + beta[col];
                if (dosilu) v = silu_f(v);
                if (pixsh) {
                    int c2 = col >> 1, rr = col & 1;
                    outf[(((size_t)b * 64 + c2) * T_LR + t) * 2 + rr] = v;
                } else {
                    size_t o = (size_t)mr * N + col;
                    if (outf) outf[o] = v;
                    if (outb) outb[o] = f2bf(v);
                }
            }
        }
    }
}

// ---------------------------------------------------------------------------
// rmsnorm over last dim (256). One wave per token. fp32 and/or bf16 out.
// ---------------------------------------------------------------------------
__global__ __launch_bounds__(256) void k_rmsnorm(const float* __restrict__ in1,
                                                 const float* __restrict__ w,
                                                 float* __restrict__ out,
                                                 unsigned short* __restrict__ out_bf,
                                                 int ntok) {
    int tok = (blockIdx.x * 256 + threadIdx.x) >> 6;
    int lane = threadIdx.x & 63;
    if (tok >= ntok) return;
    float4 v = ((const float4*)(in1 + (size_t)tok * DM))[lane];
    float ss = v.x * v.x + v.y * v.y + v.z * v.z + v.w * v.w;
    #pragma unroll
    for (int off = 32; off > 0; off >>= 1) ss += __shfl_xor(ss, off);
    float sc = rsqrtf(ss * (1.f / 256.f) + 1e-6f);
    float4 wv = ((const float4*)w)[lane];
    float4 o;
    o.x = v.x * sc * wv.x; o.y = v.y * sc * wv.y;
    o.z = v.z * sc * wv.z; o.w = v.w * sc * wv.w;
    if (out) ((float4*)(out + (size_t)tok * DM))[lane] = o;
    if (out_bf) {
        ushort4 ob;
        ob.x = f2bf(o.x); ob.y = f2bf(o.y); ob.z = f2bf(o.z); ob.w = f2bf(o.w);
        ((ushort4*)(out_bf + (size_t)tok * DM))[lane] = ob;
    }
}

// ---------------------------------------------------------------------------
// f32 -> bf16 cast (weights)
// ---------------------------------------------------------------------------
__global__ __launch_bounds__(256) void k_cast(const float* __restrict__ in,
                                              unsigned short* __restrict__ out, int n) {
    int i = blockIdx.x * 256 + threadIdx.x;
    if (i < n) out[i] = f2bf(in[i]);
}

// ---------------------------------------------------------------------------
// gate + cast: yg = bf16(y * silu(z))
// ---------------------------------------------------------------------------
__global__ __launch_bounds__(256) void k_gate_bf(const float* __restrict__ y,
                                                 const float* __restrict__ z,
                                                 unsigned short* __restrict__ yg) {
    int i = blockIdx.x * 256 + threadIdx.x;
    yg[i] = f2bf(y[i] * silu_f(z[i]));
}

// ---------------------------------------------------------------------------
// bf16 MFMA GEMM: C[M,N](f32) = A[M,K](bf16) @ Bw[N,K](bf16)^T (+res)(+C accum)
// 128x128 tile, 4 waves, each 64x64 via 4x4 mfma 16x16x32.
// ---------------------------------------------------------------------------
__global__ __launch_bounds__(256) void k_gemm_bf(const unsigned short* __restrict__ A, int lda,
                                                 const unsigned short* __restrict__ Bw,
                                                 float* C, int ldc,
                                                 const float* __restrict__ res,
                                                 int K, int arev, int crev, int accum) {
    __shared__ unsigned short As[128][40];
    __shared__ unsigned short Bs[128][40];
    int tid = threadIdx.x;
    int wave = tid >> 6, lane = tid & 63;
    int wm = (wave >> 1) * 64, wn = (wave & 1) * 64;
    int m0 = blockIdx.x * 128, n0 = blockIdx.y * 128;
    int sc = tid & 3;
    int sr = tid >> 2;
    int ar0 = m0 + sr, ar1 = m0 + sr + 64;
    if (arev) { ar0 = seqrev(ar0); ar1 = seqrev(ar1); }
    const unsigned short* ap0 = A + (size_t)ar0 * lda + sc * 8;
    const unsigned short* ap1 = A + (size_t)ar1 * lda + sc * 8;
    const unsigned short* bp0 = Bw + (size_t)(n0 + sr) * K + sc * 8;
    const unsigned short* bp1 = Bw + (size_t)(n0 + sr + 64) * K + sc * 8;
    f32x4 acc[4][4] = {};
    int q = lane >> 4, ml = lane & 15;
    for (int k0 = 0; k0 < K; k0 += 32) {
        uint4 a0 = *(const uint4*)(ap0 + k0);
        uint4 a1 = *(const uint4*)(ap1 + k0);
        uint4 b0 = *(const uint4*)(bp0 + k0);
        uint4 b1 = *(const uint4*)(bp1 + k0);
        __syncthreads();
        *(uint4*)&As[sr][sc * 8]      = a0;
        *(uint4*)&As[sr + 64][sc * 8] = a1;
        *(uint4*)&Bs[sr][sc * 8]      = b0;
        *(uint4*)&Bs[sr + 64][sc * 8] = b1;
        __syncthreads();
        bf16x8 af[4], bfr[4];
        #pragma unroll
        for (int mi = 0; mi < 4; mi++)
            af[mi] = *(const bf16x8*)&As[wm + mi * 16 + ml][q * 8];
        #pragma unroll
        for (int ni = 0; ni < 4; ni++)
            bfr[ni] = *(const bf16x8*)&Bs[wn + ni * 16 + ml][q * 8];
        #pragma unroll
        for (int mi = 0; mi < 4; mi++)
            #pragma unroll
            for (int ni = 0; ni < 4; ni++)
                acc[mi][ni] = __builtin_amdgcn_mfma_f32_16x16x32_bf16(af[mi], bfr[ni], acc[mi][ni], 0, 0, 0);
    }
    #pragma unroll
    for (int mi = 0; mi < 4; mi++) {
        #pragma unroll
        for (int r = 0; r < 4; r++) {
            int mr = m0 + wm + mi * 16 + q * 4 + r;
            int orow = crev ? seqrev(mr) : mr;
            float* crow = C + (size_t)orow * ldc;
            const float* rrow = res ? res + (size_t)orow * ldc : nullptr;
            #pragma unroll
            for (int ni = 0; ni < 4; ni++) {
                int col = n0 + wn + ni * 16 + ml;
                float v = acc[mi][ni][r];
                if (res) v += rrow[col];
                if (accum) v += crow[col];
                crow[col] = v;
            }
        }
    }
}

// ---------------------------------------------------------------------------
// generic tiled fp32 GEMM (x_proj N=48 and dt K=16)
// ---------------------------------------------------------------------------
__global__ __launch_bounds__(256) void k_gemm(const float* __restrict__ A, int lda,
                                              const float* __restrict__ Bw,
                                              float* C, int ldc,
                                              const float* __restrict__ bias,
                                              int N, int K, int act) {
    __shared__ float As[16][68];
    __shared__ float Bs[16][68];
    int bm = blockIdx.x, bn = blockIdx.y;
    int tid = threadIdx.x;
    int tx = tid & 15, ty = tid >> 4;
    int lm = tid & 63, kq = tid >> 6;
    float acc[4][4] = {};
    int arow = bm * 64 + lm;
    int brow = bn * 64 + lm;
    const float4* ap = (const float4*)(A + (size_t)arow * lda) + kq;
    bool bvalid = brow < N;
    const float4* bp = (const float4*)(Bw + (size_t)brow * K) + kq;
    for (int k0 = 0; k0 < K; k0 += 16) {
        float4 av = ap[0]; ap += 4;
        float4 bv = make_float4(0.f, 0.f, 0.f, 0.f);
        if (bvalid) { bv = bp[0]; bp += 4; }
        As[kq * 4 + 0][lm] = av.x; As[kq * 4 + 1][lm] = av.y;
        As[kq * 4 + 2][lm] = av.z; As[kq * 4 + 3][lm] = av.w;
        Bs[kq * 4 + 0][lm] = bv.x; Bs[kq * 4 + 1][lm] = bv.y;
        Bs[kq * 4 + 2][lm] = bv.z; Bs[kq * 4 + 3][lm] = bv.w;
        __syncthreads();
        #pragma unroll
        for (int kk = 0; kk < 16; kk++) {
            float4 a = *(const float4*)&As[kk][ty * 4];
            float4 b = *(const float4*)&Bs[kk][tx * 4];
            acc[0][0] += a.x * b.x; acc[0][1] += a.x * b.y; acc[0][2] += a.x * b.z; acc[0][3] += a.x * b.w;
            acc[1][0] += a.y * b.x; acc[1][1] += a.y * b.y; acc[1][2] += a.y * b.z; acc[1][3] += a.y * b.w;
            acc[2][0] += a.z * b.x; acc[2][1] += a.z * b.y; acc[2][2] += a.z * b.z; acc[2][3] += a.z * b.w;
            acc[3][0] += a.w * b.x; acc[3][1] += a.w * b.y; acc[3][2] += a.w * b.z; acc[3][3] += a.w * b.w;
        }
        __syncthreads();
    }
    #pragma unroll
    for (int i = 0; i < 4; i++) {
        int mr = bm * 64 + ty * 4 + i;
        #pragma unroll
        for (int j = 0; j < 4; j++) {
            int n = bn * 64 + tx * 4 + j;
            if (n < N) {
                float v = acc[i][j];
                if (bias) v += bias[n];
                if (act == 2) v = (v > 20.f) ? v : log1pf(__expf(v));
                C[(size_t)mr * ldc + n] = v;
            }
        }
    }
}

// ---------------------------------------------------------------------------
// depthwise causal conv k=4 + bias + silu.  xc (Tc,512) -> out (Tc,512)
// ---------------------------------------------------------------------------
__global__ __launch_bounds__(256) void k_dwconv(const float* __restrict__ xc,
                                                const float* __restrict__ cw,
                                                const float* __restrict__ cb,
                                                float* __restrict__ out) {
    int idx = blockIdx.x * 256 + threadIdx.x;   // Tc*512
    int d = idx & (DI - 1);
    int row = idx >> 9;
    int t = row % T_LR;
    float acc = cb[d];
    #pragma unroll
    for (int k = 0; k < 4; k++) {
        int tt = t - 3 + k;
        if (tt >= 0) acc += xc[(size_t)(row - t + tt) * DI + d] * cw[d * 4 + k];
    }
    out[idx] = silu_f(acc);
}

// ---------------------------------------------------------------------------
// scan phase 1: per (bl, chunk, d) thread. Chunk-local scan from h=0.
// ---------------------------------------------------------------------------
__global__ __launch_bounds__(256) void k_scan_p1(const float* __restrict__ dt,
                                                 const float* __restrict__ x,
                                                 const float* __restrict__ dbc,
                                                 const float* __restrict__ Alog,
                                                 float* __restrict__ hS,
                                                 float* __restrict__ csum) {
    int gid = blockIdx.x * 256 + threadIdx.x;   // (bl*CH + c)*DI + d
    int d = gid & (DI - 1);
    int bcix = gid >> 9;
    int c = bcix & (CH - 1);
    int bl = bcix >> 6;
    float A[DS], h[DS];
    #pragma unroll
    for (int n = 0; n < DS; n++) { A[n] = -__expf(Alog[d * DS + n]); h[n] = 0.f; }
    int tbase = c * CLEN;
    const float* dtp = dt + ((size_t)bl * T_LR + tbase) * DI + d;
    const float* xp  = x  + ((size_t)bl * T_LR + tbase) * DI + d;
    const float* bcp = dbc + ((size_t)bl * T_LR + tbase) * DBC_W;
    float S = 0.f;
    for (int t = 0; t < CLEN; t++) {
        float dtv = dtp[(size_t)t * DI];
        float xv  = xp[(size_t)t * DI];
        float dtx = dtv * xv;
        const float* bc = bcp + (size_t)t * DBC_W;
        S += dtv;
        #pragma unroll
        for (int n = 0; n < DS; n++)
            h[n] = __expf(dtv * A[n]) * h[n] + dtx * bc[16 + n];
    }
    float* hp = hS + (size_t)gid * DS;
    #pragma unroll
    for (int n = 0; n < DS; n++) hp[n] = h[n];
    csum[gid] = S;
}

// ---------------------------------------------------------------------------
// scan phase 2: per (bl, d, n) thread; sequential over CH chunks, in place.
// ---------------------------------------------------------------------------
__global__ __launch_bounds__(256) void k_scan_p2(float* __restrict__ hS,
                                                 const float* __restrict__ csum,
                                                 const float* __restrict__ Alog) {
    int gid = blockIdx.x * 256 + threadIdx.x;   // (bl*DI + d)*DS + n
    int n = gid & (DS - 1);
    int d = (gid >> 4) & (DI - 1);
    int bl = gid >> 13;
    float An = -__expf(Alog[d * DS + n]);
    float hs = 0.f;
    for (int c = 0; c < CH; c++) {
        size_t base = ((size_t)(bl * CH + c) * DI + d);
        float he = hS[base * DS + n];
        float S  = csum[base];
        hS[base * DS + n] = hs;
        hs = __expf(An * S) * hs + he;
    }
}

// ---------------------------------------------------------------------------
// scan phase 3: corrected chunk-start state, emits y in place over x.
// ---------------------------------------------------------------------------
__global__ __launch_bounds__(256) void k_scan_p3(const float* __restrict__ dt,
                                                 float* x,
                                                 const float* __restrict__ dbc,
                                                 const float* __restrict__ Alog,
                                                 const float* __restrict__ Dp,
                                                 const float* __restrict__ hS) {
    int gid = blockIdx.x * 256 + threadIdx.x;   // (bl*CH + c)*DI + d
    int d = gid & (DI - 1);
    int bcix = gid >> 9;
    int c = bcix & (CH - 1);
    int bl = bcix >> 6;
    float A[DS], h[DS];
    const float* hp = hS + (size_t)gid * DS;
    #pragma unroll
    for (int n = 0; n < DS; n++) { A[n] = -__expf(Alog[d * DS + n]); h[n] = hp[n]; }
    float Dd = Dp[d];
    int tbase = c * CLEN;
    const float* dtp = dt + ((size_t)bl * T_LR + tbase) * DI + d;
    float* xp  = x  + ((size_t)bl * T_LR + tbase) * DI + d;
    const float* bcp = dbc + ((size_t)bl * T_LR + tbase) * DBC_W;
    for (int t = 0; t < CLEN; t++) {
        float dtv = dtp[(size_t)t * DI];
        float xv  = xp[(size_t)t * DI];
        float dtx = dtv * xv;
        const float* bc = bcp + (size_t)t * DBC_W;
        float acc = 0.f;
        #pragma unroll
        for (int n = 0; n < DS; n++) {
            h[n] = __expf(dtv * A[n]) * h[n] + dtx * bc[16 + n];
            acc += h[n] * bc[32 + n];
        }
        xp[(size_t)t * DI] = acc + xv * Dd;
    }
}

// ---------------------------------------------------------------------------
extern "C" void kernel_launch(void* const* d_in, const int* in_sizes, int n_in,
                              void* d_out, int out_size, void* d_ws, size_t ws_size,
                              hipStream_t stream) {
    const float* x       = (const float*)d_in[0];
    const float* enc_w1  = (const float*)d_in[1];
    const float* enc_b1  = (const float*)d_in[2];
    const float* enc_w2  = (const float*)d_in[3];
    const float* enc_b2  = (const float*)d_in[4];
    const float* norm1_w = (const float*)d_in[5];
    const float* norm2_w = (const float*)d_in[6];
    const float* convd_w = (const float*)d_in[25];
    const float* convd_b = (const float*)d_in[26];
    const float* bn_g    = (const float*)d_in[27];
    const float* bn_b    = (const float*)d_in[28];
    const float* bn_mean = (const float*)d_in[29];
    const float* bn_var  = (const float*)d_in[30];
    const float* sp_w    = (const float*)d_in[31];
    const float* sp_b    = (const float*)d_in[32];
    float* out = (float*)d_out;

    // ---- workspace layout (float slots) ----
    float* ws = (float*)d_ws;
    size_t availf = ws_size / sizeof(float);
    size_t o = 0;
    float* t_buf  = ws + o; o += (size_t)BT * DM;
    float* xn_buf = ws + o; o += (size_t)BT * DM;       // later: comb_bf overlay
    float* mo     = ws + o; o += (size_t)BT * DM;       // early: xt/e1t; late: d_bf overlay
    unsigned short* xn_bf = (unsigned short*)(ws + o); o += (size_t)BT * DM / 2;
    unsigned short* tb_bf = (unsigned short*)(ws + o); o += (size_t)BT * DM / 2;
    unsigned short* inW_bf  = (unsigned short*)(ws + o); o += (1024 * DM) / 2;
    unsigned short* outW_bf = (unsigned short*)(ws + o); o += (DM * DI) / 2;
    unsigned short* W1r  = (unsigned short*)(ws + o); o += (3 * 128 * 64) / 2;
    unsigned short* W2r  = (unsigned short*)(ws + o); o += (3 * 256 * 128) / 2;
    unsigned short* Wdr  = (unsigned short*)(ws + o); o += (3 * 256 * 512) / 2;
    unsigned short* Wspr = (unsigned short*)(ws + o); o += (3 * 128 * 256) / 2;
    float* alpha_d = ws + o; o += 256;
    float* beta_d  = ws + o; o += 256;
    size_t persist = o;
    float* scratch = ws + persist;
    size_t scratch_avail = (availf > persist) ? (availf - persist) : 0;
    size_t per_b = (size_t)T_LR * DI * 2 + (size_t)T_LR * DBC_W
                 + (size_t)CH * DI * (DS + 1) + (size_t)T_LR * DI / 2;
    int Bc = 16;
    while (Bc > 1 && (size_t)Bc * per_b > scratch_avail) Bc >>= 1;

    // encoder temporaries overlay mo (dead until out_proj accumulation)
    unsigned short* xt  = (unsigned short*)mo;                        // (b,T,64) bf16
    unsigned short* e1t = (unsigned short*)(mo + (size_t)BT * 64 / 2); // (b,T,128) bf16
    unsigned short* comb_bf = (unsigned short*)xn_buf;   // overlay after xn dead
    unsigned short* d_bf = (unsigned short*)mo;          // overlay after mo dead

    // weight prep
    k_wrearr<<<(128 * 64 + 255) / 256, 256, 0, stream>>>(enc_w1, W1r, 128, 64);
    k_wrearr<<<(256 * 128 + 255) / 256, 256, 0, stream>>>(enc_w2, W2r, 256, 128);
    k_wrearr<<<(256 * 512 + 255) / 256, 256, 0, stream>>>(convd_w, Wdr, 256, 512);
    k_wrearr<<<(128 * 256 + 255) / 256, 256, 0, stream>>>(sp_w, Wspr, 128, 256);
    k_bnfold<<<1, 256, 0, stream>>>(convd_b, bn_g, bn_b, bn_mean, bn_var, alpha_d, beta_d);

    // encoder: transpose x -> bf16, enc1 conv (MFMA), enc2 conv (MFMA)
    k_transp<<<dim3(T_LR / 32, 2, B_SZ), 256, 0, stream>>>(x, xt, 64);
    k_conv3_bf<<<dim3(BT / 128, 1), 256, 0, stream>>>(xt, 64, nullptr, 0, W1r,
                                                      nullptr, enc_b1, nullptr, e1t, 128, 1, 0);
    k_conv3_bf<<<dim3(BT / 128, 2), 256, 0, stream>>>(e1t, 128, nullptr, 0, W2r,
                                                      nullptr, enc_b2, t_buf, tb_bf, 256, 1, 0);
    k_rmsnorm<<<BT / 4, 256, 0, stream>>>(t_buf, norm1_w, xn_buf, xn_bf, BT);

    for (int dir = 0; dir < 2; dir++) {
        const float* inW   = (const float*)d_in[7 + 9 * dir];
        const float* convW = (const float*)d_in[8 + 9 * dir];
        const float* convb = (const float*)d_in[9 + 9 * dir];
        const float* xW    = (const float*)d_in[10 + 9 * dir];
        const float* dtW   = (const float*)d_in[11 + 9 * dir];
        const float* dtb   = (const float*)d_in[12 + 9 * dir];
        const float* Alog  = (const float*)d_in[13 + 9 * dir];
        const float* Dp    = (const float*)d_in[14 + 9 * dir];
        const float* outW  = (const float*)d_in[15 + 9 * dir];
        int rev = dir;
        k_cast<<<(1024 * DM) / 256, 256, 0, stream>>>(inW, inW_bf, 1024 * DM);
        k_cast<<<(DM * DI) / 256, 256, 0, stream>>>(outW, outW_bf, DM * DI);
        for (int b0 = 0; b0 < B_SZ; b0 += Bc) {
            int Tc = Bc * T_LR;
            float* P1  = scratch;
            float* P2  = scratch + (size_t)Tc * DI;
            float* db  = scratch + 2 * (size_t)Tc * DI;
            float* hS  = db + (size_t)Tc * DBC_W;
            float* csum = hS + (size_t)Bc * CH * DI * DS;
            unsigned short* yg_bf = (unsigned short*)(csum + (size_t)Bc * CH * DI);
            const float*          xnC  = xn_buf + (size_t)b0 * T_LR * DM;
            const unsigned short* xnbC = xn_bf  + (size_t)b0 * T_LR * DM;
            float*                moC  = mo     + (size_t)b0 * T_LR * DM;
            // xc_pre = xn(rev) @ inW[0:512]^T -> P1   [MFMA]
            k_gemm_bf<<<dim3(Tc / 128, DI / 128), 256, 0, stream>>>(
                xnbC, DM, inW_bf, P1, DI, nullptr, DM, rev, 0, 0);
            // depthwise conv + silu -> P2
            k_dwconv<<<((size_t)Tc * DI) / 256, 256, 0, stream>>>(P1, convW, convb, P2);
            // dbc = xcs @ xW^T -> db  [fp32, N=48]
            k_gemm<<<dim3(Tc / 64, 1), 256, 0, stream>>>(P2, DI, xW, db, DBC_W,
                                                         nullptr, DBC_W, DI, 0);
            // dt = softplus(dbc[:,:16] @ dtW^T + dtb) -> P1  [fp32, K=16]
            k_gemm<<<dim3(Tc / 64, 8), 256, 0, stream>>>(db, DBC_W, dtW, P1, DI,
                                                         dtb, DI, DTR, 2);
            // chunked scan; y in place over P2
            k_scan_p1<<<(Bc * CH * DI) / 256, 256, 0, stream>>>(P1, P2, db, Alog, hS, csum);
            k_scan_p2<<<(Bc * DI * DS) / 256, 256, 0, stream>>>(hS, csum, Alog);
            k_scan_p3<<<(Bc * CH * DI) / 256, 256, 0, stream>>>(P1, P2, db, Alog, Dp, hS);
            // z = xn(rev) @ inW[512:1024]^T -> P1   [MFMA]
            k_gemm_bf<<<dim3(Tc / 128, DI / 128), 256, 0, stream>>>(
                xnbC, DM, inW_bf + (size_t)DI * DM, P1, DI, nullptr, DM, rev, 0, 0);
            // yg = bf16(y * silu(z))
            k_gate_bf<<<((size_t)Tc * DI) / 256, 256, 0, stream>>>(P2, P1, yg_bf);
            // mo (+)= yg @ outW^T + xn   [MFMA]
            k_gemm_bf<<<dim3(Tc / 128, DM / 128), 256, 0, stream>>>(
                yg_bf, DI, outW_bf, moC, DM, xnC, DI, 0, rev, dir);
        }
    }

    // combined = rmsnorm(mo) -> comb_bf (xn_buf overlay; xn dead)
    k_rmsnorm<<<BT / 4, 256, 0, stream>>>(mo, norm2_w, nullptr, comb_bf, BT);
    // convd + bn + silu -> d_bf (mo overlay; mo dead)   [MFMA implicit conv]
    k_conv3_bf<<<dim3(BT / 128, 2), 256, 0, stream>>>(comb_bf, 256, tb_bf, 256, Wdr,
                                                      alpha_d, beta_d, nullptr, d_bf, 256, 1, 0);
    // sp conv + pixel shuffle -> out   [MFMA implicit conv]
    k_conv3_bf<<<dim3(BT / 128, 1), 256, 0, stream>>>(d_bf, 256, nullptr, 0, Wspr,
                                                      nullptr, sp_b, out, nullptr, 128, 0, 1);
}

// Round 8
// 1728.075 us; speedup vs baseline: 5.9449x; 1.3383x over previous
//
#include <hip/hip_runtime.h>
#include <hip/hip_bf16.h>
#include <math.h>

#define B_SZ 16
#define T_LR 2560
#define BT (B_SZ * T_LR)     // 40960 tokens
#define DM 256               // d_model
#define DI 512               // d_inner
#define DS 16                // d_state
#define DTR 16               // dt_rank
#define CH 64                // scan chunks per sequence
#define CLEN (T_LR / CH)     // 40 steps per chunk

typedef __attribute__((ext_vector_type(8))) short bf16x8;
typedef __attribute__((ext_vector_type(4))) float f32x4;

__device__ __forceinline__ float silu_f(float x) {
    return x / (1.f + __expf(-x));
}
__device__ __forceinline__ unsigned short f2bf(float v) {
    __hip_bfloat16 h = __float2bfloat16(v);
    return *(unsigned short*)&h;
}
__device__ __forceinline__ float bf2f(unsigned short u) {
    union { unsigned int i; float f; } c;
    c.i = (unsigned int)u << 16;
    return c.f;
}
__device__ __forceinline__ int seqrev(int r) {
    int s = r / T_LR, t = r % T_LR;
    return s * T_LR + (T_LR - 1 - t);
}

// ---------------------------------------------------------------------------
// transpose (b,nch,T) f32 -> (b,T,nch) bf16
// ---------------------------------------------------------------------------
__global__ __launch_bounds__(256) void k_transp(const float* __restrict__ in,
                                                unsigned short* __restrict__ outb,
                                                int nch) {
    __shared__ float s[32][33];
    int b = blockIdx.z;
    int t0 = blockIdx.x * 32, c0 = blockIdx.y * 32;
    int tx = threadIdx.x & 31, ty = threadIdx.x >> 5;   // 32 x 8
    #pragma unroll
    for (int j = 0; j < 4; j++) {
        int c = c0 + ty + j * 8;
        s[ty + j * 8][tx] = in[((size_t)b * nch + c) * T_LR + t0 + tx];
    }
    __syncthreads();
    #pragma unroll
    for (int j = 0; j < 4; j++) {
        int t = t0 + ty + j * 8;
        outb[((size_t)b * T_LR + t) * nch + c0 + tx] = f2bf(s[tx][ty + j * 8]);
    }
}

// ---------------------------------------------------------------------------
// weight rearrange: in (N,K,3) f32 -> out [3][N][K] bf16
// ---------------------------------------------------------------------------
__global__ __launch_bounds__(256) void k_wrearr(const float* __restrict__ in,
                                                unsigned short* __restrict__ out,
                                                int N, int K) {
    int i = blockIdx.x * 256 + threadIdx.x;     // n*K + ci
    if (i >= N * K) return;
    int n = i / K, ci = i % K;
    #pragma unroll
    for (int k = 0; k < 3; k++)
        out[((size_t)k * N + n) * K + ci] = f2bf(in[((size_t)n * K + ci) * 3 + k]);
}

// ---------------------------------------------------------------------------
// fold BN into alpha/beta (256 ch): v = alpha*conv + beta
// ---------------------------------------------------------------------------
__global__ __launch_bounds__(256) void k_bnfold(const float* __restrict__ cb,
                                                const float* __restrict__ bng,
                                                const float* __restrict__ bnb,
                                                const float* __restrict__ bnm,
                                                const float* __restrict__ bnv,
                                                float* __restrict__ alpha,
                                                float* __restrict__ beta) {
    int c = threadIdx.x;
    float a = bng[c] * rsqrtf(bnv[c] + 1e-5f);
    alpha[c] = a;
    beta[c] = (cb[c] - bnm[c]) * a + bnb[c];
}

// ---------------------------------------------------------------------------
// combo weight: Wc[n][k] = sum_j dtW[n][j] * xW[j][k]   (512x512 bf16)
// ---------------------------------------------------------------------------
__global__ __launch_bounds__(256) void k_combo(const float* __restrict__ dtW,
                                               const float* __restrict__ xW,
                                               unsigned short* __restrict__ Wc) {
    int i = blockIdx.x * 256 + threadIdx.x;   // n*512 + k
    int n = i >> 9, k = i & 511;
    float v = 0.f;
    #pragma unroll
    for (int j = 0; j < 16; j++) v += dtW[n * 16 + j] * xW[j * 512 + k];
    Wc[i] = f2bf(v);
}

// ---------------------------------------------------------------------------
// f32 -> bf16 cast
// ---------------------------------------------------------------------------
__global__ __launch_bounds__(256) void k_cast(const float* __restrict__ in,
                                              unsigned short* __restrict__ out, int n) {
    int i = blockIdx.x * 256 + threadIdx.x;
    if (i < n) out[i] = f2bf(in[i]);
}

// ---------------------------------------------------------------------------
// implicit-GEMM k=3 "same" conv via MFMA (encoder/decoder convs).
// ---------------------------------------------------------------------------
__global__ __launch_bounds__(256) void k_conv3_bf(const unsigned short* __restrict__ A1, int K1,
                                                  const unsigned short* __restrict__ A2, int K2,
                                                  const unsigned short* __restrict__ W,
                                                  const float* __restrict__ alpha,
                                                  const float* __restrict__ beta,
                                                  float* __restrict__ outf,
                                                  unsigned short* __restrict__ outb,
                                                  int N, int dosilu, int pixsh) {
    int Kt = K1 + K2;
    __shared__ unsigned short As[130][40];
    __shared__ unsigned short Bs[3][128][40];
    int tid = threadIdx.x;
    int wave = tid >> 6, lane = tid & 63;
    int wm = (wave >> 1) * 64, wn = (wave & 1) * 64;
    int m0 = blockIdx.x * 128, n0 = blockIdx.y * 128;
    int b = m0 / T_LR, t0 = m0 % T_LR;
    int q = lane >> 4, ml = lane & 15;
    f32x4 acc[4][4] = {};
    for (int k0 = 0; k0 < Kt; k0 += 32) {
        __syncthreads();
        for (int i = tid; i < 520; i += 256) {
            int row = i >> 2, cq = i & 3;
            int t = t0 - 1 + row;
            uint4 v = make_uint4(0u, 0u, 0u, 0u);
            if (t >= 0 && t < T_LR) {
                int col = k0 + cq * 8;
                const unsigned short* src = (col < K1)
                    ? A1 + (size_t)(b * T_LR + t) * K1 + col
                    : A2 + (size_t)(b * T_LR + t) * K2 + (col - K1);
                v = *(const uint4*)src;
            }
            *(uint4*)&As[row][cq * 8] = v;
        }
        for (int i = tid; i < 1536; i += 256) {
            int tap = i >> 9;
            int r = (i >> 2) & 127;
            int cq = i & 3;
            *(uint4*)&Bs[tap][r][cq * 8] =
                *(const uint4*)(W + ((size_t)tap * N + n0 + r) * Kt + k0 + cq * 8);
        }
        __syncthreads();
        #pragma unroll
        for (int tap = 0; tap < 3; tap++) {
            bf16x8 bfr[4];
            #pragma unroll
            for (int ni = 0; ni < 4; ni++)
                bfr[ni] = *(const bf16x8*)&Bs[tap][wn + ni * 16 + ml][q * 8];
            #pragma unroll
            for (int mi = 0; mi < 4; mi++) {
                bf16x8 af = *(const bf16x8*)&As[wm + mi * 16 + ml + tap][q * 8];
                #pragma unroll
                for (int ni = 0; ni < 4; ni++)
                    acc[mi][ni] = __builtin_amdgcn_mfma_f32_16x16x32_bf16(af, bfr[ni], acc[mi][ni], 0, 0, 0);
            }
        }
    }
    #pragma unroll
    for (int mi = 0; mi < 4; mi++) {
        #pragma unroll
        for (int r = 0; r < 4; r++) {
            int mr = m0 + wm + mi * 16 + q * 4 + r;
            int t = mr - b * T_LR;
            #pragma unroll
            for (int ni = 0; ni < 4; ni++) {
                int col = n0 + wn + ni * 16 + ml;
                float a = alpha ? alpha[col] : 1.f;
                float v = acc[mi][ni][r] * a + beta[col];
                if (dosilu) v = silu_f(v);
                if (pixsh) {
                    int c2 = col >> 1, rr = col & 1;
                    outf[(((size_t)b * 64 + c2) * T_LR + t) * 2 + rr] = v;
                } else {
                    size_t o = (size_t)mr * N + col;
                    if (outf) outf[o] = v;
                    if (outb) outb[o] = f2bf(v);
                }
            }
        }
    }
}

// ---------------------------------------------------------------------------
// fused in_proj (xc half) + causal depthwise conv k=4 + silu -> xcs bf16.
// Tile 128 output rows x 128 of N=512 cols. 3 halo rows recomputed via VALU.
// ---------------------------------------------------------------------------
__global__ __launch_bounds__(256) void k_inproj_conv(const unsigned short* __restrict__ xn,
                                                     const unsigned short* __restrict__ inW,
                                                     const float* __restrict__ cw,
                                                     const float* __restrict__ cb,
                                                     unsigned short* __restrict__ xcs,
                                                     int arev) {
    __shared__ unsigned short As[128][40];
    __shared__ unsigned short Bs[128][40];
    __shared__ unsigned short Ct[131][136];   // rows: internal t0-3 .. t0+127
    int tid = threadIdx.x;
    int wave = tid >> 6, lane = tid & 63;
    int wm = (wave >> 1) * 64, wn = (wave & 1) * 64;
    int m0 = blockIdx.x * 128, n0 = blockIdx.y * 128;
    int b = m0 / T_LR, t0 = m0 % T_LR;
    int sc = tid & 3, sr = tid >> 2;
    int ar0 = m0 + sr, ar1 = m0 + sr + 64;
    if (arev) { ar0 = seqrev(ar0); ar1 = seqrev(ar1); }
    const unsigned short* ap0 = xn + (size_t)ar0 * DM + sc * 8;
    const unsigned short* ap1 = xn + (size_t)ar1 * DM + sc * 8;
    const unsigned short* bp0 = inW + (size_t)(n0 + sr) * DM + sc * 8;
    const unsigned short* bp1 = inW + (size_t)(n0 + sr + 64) * DM + sc * 8;
    f32x4 acc[4][4] = {};
    int q = lane >> 4, ml = lane & 15;
    for (int k0 = 0; k0 < DM; k0 += 32) {
        uint4 a0 = *(const uint4*)(ap0 + k0);
        uint4 a1 = *(const uint4*)(ap1 + k0);
        uint4 b0 = *(const uint4*)(bp0 + k0);
        uint4 b1 = *(const uint4*)(bp1 + k0);
        __syncthreads();
        *(uint4*)&As[sr][sc * 8]      = a0;
        *(uint4*)&As[sr + 64][sc * 8] = a1;
        *(uint4*)&Bs[sr][sc * 8]      = b0;
        *(uint4*)&Bs[sr + 64][sc * 8] = b1;
        __syncthreads();
        bf16x8 af[4], bfr[4];
        #pragma unroll
        for (int mi = 0; mi < 4; mi++)
            af[mi] = *(const bf16x8*)&As[wm + mi * 16 + ml][q * 8];
        #pragma unroll
        for (int ni = 0; ni < 4; ni++)
            bfr[ni] = *(const bf16x8*)&Bs[wn + ni * 16 + ml][q * 8];
        #pragma unroll
        for (int mi = 0; mi < 4; mi++)
            #pragma unroll
            for (int ni = 0; ni < 4; ni++)
                acc[mi][ni] = __builtin_amdgcn_mfma_f32_16x16x32_bf16(af[mi], bfr[ni], acc[mi][ni], 0, 0, 0);
    }
    // main tile -> Ct rows 3..130
    #pragma unroll
    for (int mi = 0; mi < 4; mi++)
        #pragma unroll
        for (int r = 0; r < 4; r++)
            #pragma unroll
            for (int ni = 0; ni < 4; ni++)
                Ct[3 + wm + mi * 16 + q * 4 + r][wn + ni * 16 + ml] = f2bf(acc[mi][ni][r]);
    // halo rows 0..2 (internal t0-3..t0-1) via direct dot — 384 items on 256 threads
    for (int i = tid; i < 384; i += 256) {
        int hr = i >> 7, c = i & 127;
        int tr = t0 - 3 + hr;
        float v = 0.f;
        if (tr >= 0) {
            int src = b * T_LR + (arev ? (T_LR - 1 - tr) : tr);
            const unsigned short* xr = xn + (size_t)src * DM;
            const unsigned short* wr = inW + (size_t)(n0 + c) * DM;
            for (int k = 0; k < DM; k += 8) {
                uint4 xa = *(const uint4*)(xr + k);
                uint4 wa = *(const uint4*)(wr + k);
                const unsigned short* xs = (const unsigned short*)&xa;
                const unsigned short* wsp = (const unsigned short*)&wa;
                #pragma unroll
                for (int j = 0; j < 8; j++) v += bf2f(xs[j]) * bf2f(wsp[j]);
            }
        }
        Ct[hr][c] = f2bf(v);
    }
    __syncthreads();
    // causal conv k=4 + silu, write xcs bf16
    int col = tid & 127;
    int d = n0 + col;
    float w0 = cw[d * 4 + 0], w1 = cw[d * 4 + 1], w2 = cw[d * 4 + 2], w3 = cw[d * 4 + 3];
    float bi = cb[d];
    int rbase = tid >> 7;
    for (int j = 0; j < 64; j++) {
        int row = rbase + 2 * j;
        float v = bi + bf2f(Ct[row][col]) * w0 + bf2f(Ct[row + 1][col]) * w1
                     + bf2f(Ct[row + 2][col]) * w2 + bf2f(Ct[row + 3][col]) * w3;
        xcs[(size_t)(m0 + row) * DI + d] = f2bf(silu_f(v));
    }
}

// ---------------------------------------------------------------------------
// rmsnorm over last dim (256). One wave per token. fp32 and/or bf16 out.
// ---------------------------------------------------------------------------
__global__ __launch_bounds__(256) void k_rmsnorm(const float* __restrict__ in1,
                                                 const float* __restrict__ w,
                                                 float* __restrict__ out,
                                                 unsigned short* __restrict__ out_bf,
                                                 int ntok) {
    int tok = (blockIdx.x * 256 + threadIdx.x) >> 6;
    int lane = threadIdx.x & 63;
    if (tok >= ntok) return;
    float4 v = ((const float4*)(in1 + (size_t)tok * DM))[lane];
    float ss = v.x * v.x + v.y * v.y + v.z * v.z + v.w * v.w;
    #pragma unroll
    for (int off = 32; off > 0; off >>= 1) ss += __shfl_xor(ss, off);
    float sc = rsqrtf(ss * (1.f / 256.f) + 1e-6f);
    float4 wv = ((const float4*)w)[lane];
    float4 o;
    o.x = v.x * sc * wv.x; o.y = v.y * sc * wv.y;
    o.z = v.z * sc * wv.z; o.w = v.w * sc * wv.w;
    if (out) ((float4*)(out + (size_t)tok * DM))[lane] = o;
    if (out_bf) {
        ushort4 ob;
        ob.x = f2bf(o.x); ob.y = f2bf(o.y); ob.z = f2bf(o.z); ob.w = f2bf(o.w);
        ((ushort4*)(out_bf + (size_t)tok * DM))[lane] = ob;
    }
}

// ---------------------------------------------------------------------------
// bf16 MFMA GEMM, swiss-army epilogue:
// C = A[M,K] @ Bw[Nout<=128*gy,K]^T ; v += bias; act==2 -> softplus;
// gate -> v = silu(v)*gate[row,col]; res -> +res; accum -> +Cf;
// stores: Cf fp32 and/or Cb bf16 (ld=ldc). arev/crev time-reversal.
// ---------------------------------------------------------------------------
__global__ __launch_bounds__(256) void k_gemm_bf(const unsigned short* __restrict__ A, int lda,
                                                 const unsigned short* __restrict__ Bw,
                                                 float* Cf, unsigned short* Cb, int ldc,
                                                 const float* __restrict__ res,
                                                 const float* __restrict__ bias,
                                                 const unsigned short* __restrict__ gate,
                                                 int K, int Nout, int act,
                                                 int arev, int crev, int accum) {
    __shared__ unsigned short As[128][40];
    __shared__ unsigned short Bs[128][40];
    int tid = threadIdx.x;
    int wave = tid >> 6, lane = tid & 63;
    int wm = (wave >> 1) * 64, wn = (wave & 1) * 64;
    int m0 = blockIdx.x * 128, n0 = blockIdx.y * 128;
    int sc = tid & 3, sr = tid >> 2;
    int ar0 = m0 + sr, ar1 = m0 + sr + 64;
    if (arev) { ar0 = seqrev(ar0); ar1 = seqrev(ar1); }
    const unsigned short* ap0 = A + (size_t)ar0 * lda + sc * 8;
    const unsigned short* ap1 = A + (size_t)ar1 * lda + sc * 8;
    bool bv0 = (n0 + sr) < Nout;
    bool bv1 = (n0 + sr + 64) < Nout;
    const unsigned short* bp0 = Bw + (size_t)(n0 + sr) * K + sc * 8;
    const unsigned short* bp1 = Bw + (size_t)(n0 + sr + 64) * K + sc * 8;
    f32x4 acc[4][4] = {};
    int q = lane >> 4, ml = lane & 15;
    for (int k0 = 0; k0 < K; k0 += 32) {
        uint4 a0 = *(const uint4*)(ap0 + k0);
        uint4 a1 = *(const uint4*)(ap1 + k0);
        uint4 b0 = make_uint4(0u, 0u, 0u, 0u), b1 = make_uint4(0u, 0u, 0u, 0u);
        if (bv0) b0 = *(const uint4*)(bp0 + k0);
        if (bv1) b1 = *(const uint4*)(bp1 + k0);
        __syncthreads();
        *(uint4*)&As[sr][sc * 8]      = a0;
        *(uint4*)&As[sr + 64][sc * 8] = a1;
        *(uint4*)&Bs[sr][sc * 8]      = b0;
        *(uint4*)&Bs[sr + 64][sc * 8] = b1;
        __syncthreads();
        bf16x8 af[4], bfr[4];
        #pragma unroll
        for (int mi = 0; mi < 4; mi++)
            af[mi] = *(const bf16x8*)&As[wm + mi * 16 + ml][q * 8];
        #pragma unroll
        for (int ni = 0; ni < 4; ni++)
            bfr[ni] = *(const bf16x8*)&Bs[wn + ni * 16 + ml][q * 8];
        #pragma unroll
        for (int mi = 0; mi < 4; mi++)
            #pragma unroll
            for (int ni = 0; ni < 4; ni++)
                acc[mi][ni] = __builtin_amdgcn_mfma_f32_16x16x32_bf16(af[mi], bfr[ni], acc[mi][ni], 0, 0, 0);
    }
    #pragma unroll
    for (int mi = 0; mi < 4; mi++) {
        #pragma unroll
        for (int r = 0; r < 4; r++) {
            int mr = m0 + wm + mi * 16 + q * 4 + r;
            int orow = crev ? seqrev(mr) : mr;
            #pragma unroll
            for (int ni = 0; ni < 4; ni++) {
                int col = n0 + wn + ni * 16 + ml;
                if (col < Nout) {
                    float v = acc[mi][ni][r];
                    if (bias) v += bias[col];
                    if (act == 2) v = (v > 20.f) ? v : log1pf(__expf(v));
                    if (gate) v = silu_f(v) * bf2f(gate[(size_t)mr * ldc + col]);
                    if (res) v += res[(size_t)orow * ldc + col];
                    if (accum) v += Cf[(size_t)orow * ldc + col];
                    if (Cf) Cf[(size_t)orow * ldc + col] = v;
                    if (Cb) Cb[(size_t)orow * ldc + col] = f2bf(v);
                }
            }
        }
    }
}

// ---------------------------------------------------------------------------
// scan phase 1: per (bl, chunk, d) thread. Chunk-local scan from h=0.
// dt, x are bf16 (stride DI); db fp32 (stride 32: B=cols 0..16, C=16..32)
// ---------------------------------------------------------------------------
__global__ __launch_bounds__(256) void k_scan_p1(const unsigned short* __restrict__ dt,
                                                 const unsigned short* __restrict__ x,
                                                 const float* __restrict__ db,
                                                 const float* __restrict__ Alog,
                                                 float* __restrict__ hS,
                                                 float* __restrict__ csum) {
    int gid = blockIdx.x * 256 + threadIdx.x;   // (bl*CH + c)*DI + d
    int d = gid & (DI - 1);
    int bcix = gid >> 9;
    int c = bcix & (CH - 1);
    int bl = bcix >> 6;
    float A[DS], h[DS];
    #pragma unroll
    for (int n = 0; n < DS; n++) { A[n] = -__expf(Alog[d * DS + n]); h[n] = 0.f; }
    int tbase = c * CLEN;
    const unsigned short* dtp = dt + ((size_t)bl * T_LR + tbase) * DI + d;
    const unsigned short* xp  = x  + ((size_t)bl * T_LR + tbase) * DI + d;
    const float* bcp = db + ((size_t)bl * T_LR + tbase) * 32;
    float S = 0.f;
    for (int t = 0; t < CLEN; t++) {
        float dtv = bf2f(dtp[(size_t)t * DI]);
        float xv  = bf2f(xp[(size_t)t * DI]);
        float dtx = dtv * xv;
        const float* bc = bcp + (size_t)t * 32;
        S += dtv;
        #pragma unroll
        for (int n = 0; n < DS; n++)
            h[n] = __expf(dtv * A[n]) * h[n] + dtx * bc[n];
    }
    float* hp = hS + (size_t)gid * DS;
    #pragma unroll
    for (int n = 0; n < DS; n++) hp[n] = h[n];
    csum[gid] = S;
}

// ---------------------------------------------------------------------------
// scan phase 2: per (bl, d, n) thread; sequential over CH chunks, in place.
// ---------------------------------------------------------------------------
__global__ __launch_bounds__(256) void k_scan_p2(float* __restrict__ hS,
                                                 const float* __restrict__ csum,
                                                 const float* __restrict__ Alog) {
    int gid = blockIdx.x * 256 + threadIdx.x;   // (bl*DI + d)*DS + n
    int n = gid & (DS - 1);
    int d = (gid >> 4) & (DI - 1);
    int bl = gid >> 13;
    float An = -__expf(Alog[d * DS + n]);
    float hs = 0.f;
    for (int c = 0; c < CH; c++) {
        size_t base = ((size_t)(bl * CH + c) * DI + d);
        float he = hS[base * DS + n];
        float S  = csum[base];
        hS[base * DS + n] = hs;
        hs = __expf(An * S) * hs + he;
    }
}

// ---------------------------------------------------------------------------
// scan phase 3: corrected chunk-start state; y written bf16 in place over x.
// ---------------------------------------------------------------------------
__global__ __launch_bounds__(256) void k_scan_p3(const unsigned short* __restrict__ dt,
                                                 unsigned short* x,
                                                 const float* __restrict__ db,
                                                 const float* __restrict__ Alog,
                                                 const float* __restrict__ Dp,
                                                 const float* __restrict__ hS) {
    int gid = blockIdx.x * 256 + threadIdx.x;   // (bl*CH + c)*DI + d
    int d = gid & (DI - 1);
    int bcix = gid >> 9;
    int c = bcix & (CH - 1);
    int bl = bcix >> 6;
    float A[DS], h[DS];
    const float* hp = hS + (size_t)gid * DS;
    #pragma unroll
    for (int n = 0; n < DS; n++) { A[n] = -__expf(Alog[d * DS + n]); h[n] = hp[n]; }
    float Dd = Dp[d];
    int tbase = c * CLEN;
    const unsigned short* dtp = dt + ((size_t)bl * T_LR + tbase) * DI + d;
    unsigned short* xp = x + ((size_t)bl * T_LR + tbase) * DI + d;
    const float* bcp = db + ((size_t)bl * T_LR + tbase) * 32;
    for (int t = 0; t < CLEN; t++) {
        float dtv = bf2f(dtp[(size_t)t * DI]);
        float xv  = bf2f(xp[(size_t)t * DI]);
        float dtx = dtv * xv;
        const float* bc = bcp + (size_t)t * 32;
        float acc = 0.f;
        #pragma unroll
        for (int n = 0; n < DS; n++) {
            h[n] = __expf(dtv * A[n]) * h[n] + dtx * bc[n];
            acc += h[n] * bc[16 + n];
        }
        xp[(size_t)t * DI] = f2bf(acc + xv * Dd);
    }
}

// ---------------------------------------------------------------------------
extern "C" void kernel_launch(void* const* d_in, const int* in_sizes, int n_in,
                              void* d_out, int out_size, void* d_ws, size_t ws_size,
                              hipStream_t stream) {
    const float* x       = (const float*)d_in[0];
    const float* enc_w1  = (const float*)d_in[1];
    const float* enc_b1  = (const float*)d_in[2];
    const float* enc_w2  = (const float*)d_in[3];
    const float* enc_b2  = (const float*)d_in[4];
    const float* norm1_w = (const float*)d_in[5];
    const float* norm2_w = (const float*)d_in[6];
    const float* convd_w = (const float*)d_in[25];
    const float* convd_b = (const float*)d_in[26];
    const float* bn_g    = (const float*)d_in[27];
    const float* bn_b    = (const float*)d_in[28];
    const float* bn_mean = (const float*)d_in[29];
    const float* bn_var  = (const float*)d_in[30];
    const float* sp_w    = (const float*)d_in[31];
    const float* sp_b    = (const float*)d_in[32];
    float* out = (float*)d_out;

    // ---- workspace layout (float slots) ----
    float* ws = (float*)d_ws;
    size_t availf = ws_size / sizeof(float);
    size_t o = 0;
    float* t_buf  = ws + o; o += (size_t)BT * DM;
    float* xn_buf = ws + o; o += (size_t)BT * DM;       // later: comb_bf overlay
    float* mo     = ws + o; o += (size_t)BT * DM;       // early: xt/e1t; late: d_bf overlay
    unsigned short* xn_bf = (unsigned short*)(ws + o); o += (size_t)BT * DM / 2;
    unsigned short* tb_bf = (unsigned short*)(ws + o); o += (size_t)BT * DM / 2;
    unsigned short* inW_bf  = (unsigned short*)(ws + o); o += (1024 * DM) / 2;
    unsigned short* outW_bf = (unsigned short*)(ws + o); o += (DM * DI) / 2;
    unsigned short* Wcombo  = (unsigned short*)(ws + o); o += (DI * DI) / 2;
    unsigned short* xW_bc   = (unsigned short*)(ws + o); o += (32 * DI) / 2;
    unsigned short* W1r  = (unsigned short*)(ws + o); o += (3 * 128 * 64) / 2;
    unsigned short* W2r  = (unsigned short*)(ws + o); o += (3 * 256 * 128) / 2;
    unsigned short* Wdr  = (unsigned short*)(ws + o); o += (3 * 256 * 512) / 2;
    unsigned short* Wspr = (unsigned short*)(ws + o); o += (3 * 128 * 256) / 2;
    float* alpha_d = ws + o; o += 256;
    float* beta_d  = ws + o; o += 256;
    size_t persist = o;
    float* scratch = ws + persist;
    size_t scratch_avail = (availf > persist) ? (availf - persist) : 0;
    // per-batch scratch (float slots): xcs bf16 + dt bf16 + db f32 + hS + csum
    size_t per_b = (size_t)T_LR * DI / 2 * 2 + (size_t)T_LR * 32
                 + (size_t)CH * DI * (DS + 1);
    int Bc = 16;
    while (Bc > 1 && (size_t)Bc * per_b > scratch_avail) Bc >>= 1;

    // encoder temporaries overlay mo (dead until out_proj accumulation)
    unsigned short* xt  = (unsigned short*)mo;                         // (b,T,64) bf16
    unsigned short* e1t = (unsigned short*)(mo + (size_t)BT * 64 / 2); // (b,T,128) bf16
    unsigned short* comb_bf = (unsigned short*)xn_buf;   // overlay after xn dead
    unsigned short* d_bf = (unsigned short*)mo;          // overlay after mo dead

    // weight prep
    k_wrearr<<<(128 * 64 + 255) / 256, 256, 0, stream>>>(enc_w1, W1r, 128, 64);
    k_wrearr<<<(256 * 128 + 255) / 256, 256, 0, stream>>>(enc_w2, W2r, 256, 128);
    k_wrearr<<<(256 * 512 + 255) / 256, 256, 0, stream>>>(convd_w, Wdr, 256, 512);
    k_wrearr<<<(128 * 256 + 255) / 256, 256, 0, stream>>>(sp_w, Wspr, 128, 256);
    k_bnfold<<<1, 256, 0, stream>>>(convd_b, bn_g, bn_b, bn_mean, bn_var, alpha_d, beta_d);

    // encoder
    k_transp<<<dim3(T_LR / 32, 2, B_SZ), 256, 0, stream>>>(x, xt, 64);
    k_conv3_bf<<<dim3(BT / 128, 1), 256, 0, stream>>>(xt, 64, nullptr, 0, W1r,
                                                      nullptr, enc_b1, nullptr, e1t, 128, 1, 0);
    k_conv3_bf<<<dim3(BT / 128, 2), 256, 0, stream>>>(e1t, 128, nullptr, 0, W2r,
                                                      nullptr, enc_b2, t_buf, tb_bf, 256, 1, 0);
    k_rmsnorm<<<BT / 4, 256, 0, stream>>>(t_buf, norm1_w, xn_buf, xn_bf, BT);

    for (int dir = 0; dir < 2; dir++) {
        const float* inW   = (const float*)d_in[7 + 9 * dir];
        const float* convW = (const float*)d_in[8 + 9 * dir];
        const float* convb = (const float*)d_in[9 + 9 * dir];
        const float* xW    = (const float*)d_in[10 + 9 * dir];
        const float* dtW   = (const float*)d_in[11 + 9 * dir];
        const float* dtb   = (const float*)d_in[12 + 9 * dir];
        const float* Alog  = (const float*)d_in[13 + 9 * dir];
        const float* Dp    = (const float*)d_in[14 + 9 * dir];
        const float* outW  = (const float*)d_in[15 + 9 * dir];
        int rev = dir;
        k_cast<<<(1024 * DM) / 256, 256, 0, stream>>>(inW, inW_bf, 1024 * DM);
        k_cast<<<(DM * DI) / 256, 256, 0, stream>>>(outW, outW_bf, DM * DI);
        k_cast<<<(32 * DI) / 256, 256, 0, stream>>>(xW + 16 * DI, xW_bc, 32 * DI);
        k_combo<<<(DI * DI) / 256, 256, 0, stream>>>(dtW, xW, Wcombo);
        for (int b0 = 0; b0 < B_SZ; b0 += Bc) {
            int Tc = Bc * T_LR;
            unsigned short* xcs = (unsigned short*)scratch;                       // bf16, later y
            unsigned short* dtb16 = xcs + (size_t)Tc * DI;                        // bf16, later yg
            float* db   = (float*)(dtb16 + (size_t)Tc * DI);
            float* hS   = db + (size_t)Tc * 32;
            float* csum = hS + (size_t)Bc * CH * DI * DS;
            const float*          xnC  = xn_buf + (size_t)b0 * T_LR * DM;
            const unsigned short* xnbC = xn_bf  + (size_t)b0 * T_LR * DM;
            float*                moC  = mo     + (size_t)b0 * T_LR * DM;
            // fused in_proj(xc) + causal dwconv + silu -> xcs bf16
            k_inproj_conv<<<dim3(Tc / 128, DI / 128), 256, 0, stream>>>(
                xnbC, inW_bf, convW, convb, xcs, rev);
            // dt = softplus(xcs @ Wcombo^T + dtb) -> bf16
            k_gemm_bf<<<dim3(Tc / 128, DI / 128), 256, 0, stream>>>(
                xcs, DI, Wcombo, nullptr, dtb16, DI, nullptr, dtb, nullptr,
                DI, DI, 2, 0, 0, 0);
            // db (B,C) = xcs @ xW[16:48]^T -> fp32 (Tc,32)
            k_gemm_bf<<<dim3(Tc / 128, 1), 256, 0, stream>>>(
                xcs, DI, xW_bc, db, nullptr, 32, nullptr, nullptr, nullptr,
                DI, 32, 0, 0, 0, 0);
            // chunked scan; y bf16 in place over xcs
            k_scan_p1<<<(Bc * CH * DI) / 256, 256, 0, stream>>>(dtb16, xcs, db, Alog, hS, csum);
            k_scan_p2<<<(Bc * DI * DS) / 256, 256, 0, stream>>>(hS, csum, Alog);
            k_scan_p3<<<(Bc * CH * DI) / 256, 256, 0, stream>>>(dtb16, xcs, db, Alog, Dp, hS);
            // z GEMM + gate: yg = bf16(y * silu(z)) -> overlays dt buffer
            k_gemm_bf<<<dim3(Tc / 128, DI / 128), 256, 0, stream>>>(
                xnbC, DM, inW_bf + (size_t)DI * DM, nullptr, dtb16, DI,
                nullptr, nullptr, xcs, DM, DI, 0, rev, 0, 0);
            // mo (+)= yg @ outW^T + xn
            k_gemm_bf<<<dim3(Tc / 128, DM / 128), 256, 0, stream>>>(
                dtb16, DI, outW_bf, moC, nullptr, DM, xnC, nullptr, nullptr,
                DI, DM, 0, 0, rev, dir);
        }
    }

    // combined = rmsnorm(mo) -> comb_bf (xn_buf overlay)
    k_rmsnorm<<<BT / 4, 256, 0, stream>>>(mo, norm2_w, nullptr, comb_bf, BT);
    // convd + bn + silu -> d_bf (mo overlay)
    k_conv3_bf<<<dim3(BT / 128, 2), 256, 0, stream>>>(comb_bf, 256, tb_bf, 256, Wdr,
                                                      alpha_d, beta_d, nullptr, d_bf, 256, 1, 0);
    // sp conv + pixel shuffle -> out
    k_conv3_bf<<<dim3(BT / 128, 1), 256, 0, stream>>>(d_bf, 256, nullptr, 0, Wspr,
                                                      nullptr, sp_b, out, nullptr, 128, 0, 1);
}